// Round 1
// baseline (2568.215 us; speedup 1.0000x reference)
//
#include <hip/hip_runtime.h>

#define NN 50000
#define EE 800000
#define LL 6
constexpr float EPSF = 1e-5f;

__device__ __forceinline__ float bf2f(unsigned short u) {
    union { unsigned int i; float f; } v; v.i = ((unsigned int)u) << 16; return v.f;
}
__device__ __forceinline__ unsigned short f2bf(float f) {
    union { float f; unsigned int i; } v; v.f = f;
    unsigned int r = v.i + 0x7FFFu + ((v.i >> 16) & 1u);
    return (unsigned short)(r >> 16);
}
__device__ __forceinline__ float leaky(float v, float s) { return v > 0.f ? v : s * v; }

// ---------------- GEMM: C = act( A_ln @ B + bias ) ----------------
// MODE 0: +bias only. MODE 1: +bias, *g/sqrt(1+eps)+b2, leaky 0.1. MODE 2: +bias, leaky 0.1.
constexpr int BM = 128, BN = 128, BK = 16;

template<int MODE, bool LN, bool OUT_BF16>
__global__ __launch_bounds__(256) void gemm_k(
    const float* __restrict__ A, const float* __restrict__ B,
    const float* __restrict__ bias,
    const float* __restrict__ mu, const float* __restrict__ rsig,
    const float* __restrict__ lng, const float* __restrict__ lnb,
    const float* __restrict__ g2, const float* __restrict__ b2,
    void* __restrict__ Cv, int M, int K, int N)
{
    __shared__ float As[BK][BM + 4];   // +4 keeps 16B alignment of rows
    __shared__ float Bs[BK][BN];
    const int tid = threadIdx.x;
    const int bm = blockIdx.x * BM;
    const int bn = blockIdx.y * BN;
    const int arow = tid >> 2;          // 0..63
    const int ak   = (tid & 3) << 2;    // 0,4,8,12
    const int brow = tid >> 5;          // 0..7
    const int bcol = (tid & 31) << 2;   // 0..124
    const int tx = tid & 15, ty = tid >> 4;

    float acc[8][8];
#pragma unroll
    for (int i = 0; i < 8; ++i)
#pragma unroll
        for (int j = 0; j < 8; ++j) acc[i][j] = 0.f;

    for (int k0 = 0; k0 < K; k0 += BK) {
#pragma unroll
        for (int half = 0; half < 2; ++half) {
            int r = arow + half * 64;
            int gr = bm + r;
            float4 av = make_float4(0.f, 0.f, 0.f, 0.f);
            if (gr < M) av = *(const float4*)(A + (size_t)gr * K + k0 + ak);
            if constexpr (LN) {
                float m = 0.f, rs = 0.f;
                if (gr < M) { m = mu[gr]; rs = rsig[gr]; }
                float4 gv = *(const float4*)(lng + k0 + ak);
                float4 bv = *(const float4*)(lnb + k0 + ak);
                av.x = (av.x - m) * rs * gv.x + bv.x;
                av.y = (av.y - m) * rs * gv.y + bv.y;
                av.z = (av.z - m) * rs * gv.z + bv.z;
                av.w = (av.w - m) * rs * gv.w + bv.w;
            }
            As[ak + 0][r] = av.x; As[ak + 1][r] = av.y;
            As[ak + 2][r] = av.z; As[ak + 3][r] = av.w;
        }
#pragma unroll
        for (int half = 0; half < 2; ++half) {
            int r = brow + half * 8;
            float4 bv = *(const float4*)(B + (size_t)(k0 + r) * N + bn + bcol);
            *(float4*)&Bs[r][bcol] = bv;
        }
        __syncthreads();
#pragma unroll
        for (int k = 0; k < BK; ++k) {
            float4 a0 = *(const float4*)&As[k][ty * 4];
            float4 a1 = *(const float4*)&As[k][64 + ty * 4];
            float4 b0 = *(const float4*)&Bs[k][tx * 4];
            float4 b1 = *(const float4*)&Bs[k][64 + tx * 4];
            float a[8] = {a0.x, a0.y, a0.z, a0.w, a1.x, a1.y, a1.z, a1.w};
            float b[8] = {b0.x, b0.y, b0.z, b0.w, b1.x, b1.y, b1.z, b1.w};
#pragma unroll
            for (int i = 0; i < 8; ++i)
#pragma unroll
                for (int j = 0; j < 8; ++j)
                    acc[i][j] = fmaf(a[i], b[j], acc[i][j]);
        }
        __syncthreads();
    }

    const float inv_s = 0.9999950000374997f; // 1/sqrt(1+1e-5)
#pragma unroll
    for (int i = 0; i < 8; ++i) {
        int r = bm + (i >> 2) * 64 + ty * 4 + (i & 3);
        if (r >= M) continue;
#pragma unroll
        for (int jh = 0; jh < 2; ++jh) {
            int c = bn + jh * 64 + tx * 4;
            float v[4];
#pragma unroll
            for (int j = 0; j < 4; ++j) v[j] = acc[i][jh * 4 + j];
            float4 bs = *(const float4*)(bias + c);
            v[0] += bs.x; v[1] += bs.y; v[2] += bs.z; v[3] += bs.w;
            if constexpr (MODE == 1) {
                float4 g4 = *(const float4*)(g2 + c);
                float4 bb = *(const float4*)(b2 + c);
                v[0] = v[0] * inv_s * g4.x + bb.x;
                v[1] = v[1] * inv_s * g4.y + bb.y;
                v[2] = v[2] * inv_s * g4.z + bb.z;
                v[3] = v[3] * inv_s * g4.w + bb.w;
#pragma unroll
                for (int j = 0; j < 4; ++j) v[j] = leaky(v[j], 0.1f);
            } else if constexpr (MODE == 2) {
#pragma unroll
                for (int j = 0; j < 4; ++j) v[j] = leaky(v[j], 0.1f);
            }
            if constexpr (OUT_BF16) {
                ushort4 o;
                o.x = f2bf(v[0]); o.y = f2bf(v[1]); o.z = f2bf(v[2]); o.w = f2bf(v[3]);
                *(ushort4*)((unsigned short*)Cv + (size_t)r * N + c) = o;
            } else {
                float4 o = make_float4(v[0], v[1], v[2], v[3]);
                *(float4*)((float*)Cv + (size_t)r * N + c) = o;
            }
        }
    }
}

// ---------------- LayerNorm row stats (wave per row of 256) ----------------
__global__ __launch_bounds__(256) void ln_stats_k(const float* __restrict__ h,
                                                  float* __restrict__ mu,
                                                  float* __restrict__ rsig, int N)
{
    int wv = blockIdx.x * 4 + (threadIdx.x >> 6);
    if (wv >= N) return;
    int lane = threadIdx.x & 63;
    float4 v = *(const float4*)(h + (size_t)wv * 256 + lane * 4);
    float s = v.x + v.y + v.z + v.w;
#pragma unroll
    for (int off = 1; off < 64; off <<= 1) s += __shfl_xor(s, off);
    float m = s * (1.f / 256.f);
    float d0 = v.x - m, d1 = v.y - m, d2 = v.z - m, d3 = v.w - m;
    float q = d0 * d0 + d1 * d1 + d2 * d2 + d3 * d3;
#pragma unroll
    for (int off = 1; off < 64; off <<= 1) q += __shfl_xor(q, off);
    if (lane == 0) { mu[wv] = m; rsig[wv] = rsqrtf(q * (1.f / 256.f) + EPSF); }
}

// ---------------- CSR build ----------------
__global__ __launch_bounds__(256) void hist_k(const int* __restrict__ ei, int E, int N,
                                              int* __restrict__ counts)
{
    int e = blockIdx.x * 256 + threadIdx.x;
    int Etot = E + N;
    if (e >= Etot) return;
    int d = (e < E) ? ei[E + e] : (e - E);   // edge_index row1 = dst; self-loops appended
    atomicAdd(&counts[d], 1);
}

__global__ __launch_bounds__(1024) void scan_k(const int* __restrict__ counts,
                                               int* __restrict__ offsets, int N, int Etot)
{
    __shared__ int sm[1024];
    __shared__ int carry;
    if (threadIdx.x == 0) carry = 0;
    __syncthreads();
    for (int base = 0; base < N; base += 1024) {
        int i = base + threadIdx.x;
        int v = (i < N) ? counts[i] : 0;
        sm[threadIdx.x] = v;
        __syncthreads();
        for (int off = 1; off < 1024; off <<= 1) {
            int t = (threadIdx.x >= off) ? sm[threadIdx.x - off] : 0;
            __syncthreads();
            sm[threadIdx.x] += t;
            __syncthreads();
        }
        if (i < N) offsets[i] = carry + sm[threadIdx.x] - v;   // exclusive
        __syncthreads();
        if (threadIdx.x == 0) carry += sm[1023];
        __syncthreads();
    }
    if (threadIdx.x == 0) offsets[N] = Etot;
}

__global__ __launch_bounds__(256) void scatter_k(const int* __restrict__ ei, int E, int N,
                                                 int* __restrict__ cursor, int* __restrict__ eidx)
{
    int e = blockIdx.x * 256 + threadIdx.x;
    int Etot = E + N;
    if (e >= Etot) return;
    int s, d;
    if (e < E) { s = ei[e]; d = ei[E + e]; }
    else       { s = e - E; d = s; }
    int pos = atomicAdd(&cursor[d], 1);
    eidx[pos] = s;
}

__global__ void softmax6_k(const float* __restrict__ sw, float* __restrict__ w)
{
    if (threadIdx.x == 0 && blockIdx.x == 0) {
        float m = -1e30f;
        for (int l = 0; l < LL; ++l) m = fmaxf(m, sw[l]);
        float e[LL]; float s = 0.f;
        for (int l = 0; l < LL; ++l) { e[l] = __expf(sw[l] - m); s += e[l]; }
        for (int l = 0; l < LL; ++l) w[l] = e[l] / s;
    }
}

// ---------------- Edge aggregation: one wave per node, CSR, no atomics ----------------
// lane = head*8 + c4grp; covers channels [head*32 + c4grp*4, +4). No segment-max needed:
// logits are O(±8), exp() safe in fp32 and mathematically identical to max-subtracted softmax.
__global__ __launch_bounds__(256) void edge_k(
    const unsigned short* __restrict__ xl, const unsigned short* __restrict__ xr,
    const float* __restrict__ att, const float* __restrict__ convb,
    const int* __restrict__ offsets, const int* __restrict__ eidx,
    float* __restrict__ h, float* __restrict__ hsum,
    const float* __restrict__ wsm, const float* __restrict__ scales,
    int layer, int N)
{
    int wv = blockIdx.x * 4 + (threadIdx.x >> 6);
    if (wv >= N) return;
    int lane = threadIdx.x & 63;
    float4 attv = *(const float4*)(att + lane * 4);
    ushort4 xru = *(const ushort4*)(xr + (size_t)wv * 256 + lane * 4);
    float xr0 = bf2f(xru.x), xr1 = bf2f(xru.y), xr2 = bf2f(xru.z), xr3 = bf2f(xru.w);
    int e0 = offsets[wv], e1 = offsets[wv + 1];
    float den = 0.f, a0 = 0.f, a1 = 0.f, a2 = 0.f, a3 = 0.f;
    for (int e = e0; e < e1; ++e) {
        int s = eidx[e];
        ushort4 xu = *(const ushort4*)(xl + (size_t)s * 256 + lane * 4);
        float x0 = bf2f(xu.x), x1 = bf2f(xu.y), x2 = bf2f(xu.z), x3 = bf2f(xu.w);
        float v0 = x0 + xr0; v0 = v0 > 0.f ? v0 : 0.2f * v0;
        float v1 = x1 + xr1; v1 = v1 > 0.f ? v1 : 0.2f * v1;
        float v2 = x2 + xr2; v2 = v2 > 0.f ? v2 : 0.2f * v2;
        float v3 = x3 + xr3; v3 = v3 > 0.f ? v3 : 0.2f * v3;
        float pm = attv.x * v0 + attv.y * v1 + attv.z * v2 + attv.w * v3;
        pm += __shfl_xor(pm, 1);   // reduce over the 8 lanes of this head
        pm += __shfl_xor(pm, 2);
        pm += __shfl_xor(pm, 4);
        float ex = __expf(pm);
        den += ex;
        a0 = fmaf(x0, ex, a0); a1 = fmaf(x1, ex, a1);
        a2 = fmaf(x2, ex, a2); a3 = fmaf(x3, ex, a3);
    }
    float inv = 1.f / den;   // den > 0: self-loop guarantees >=1 edge
    float4 cb = *(const float4*)(convb + lane * 4);
    float o0 = leaky(a0 * inv + cb.x, 0.1f);
    float o1 = leaky(a1 * inv + cb.y, 0.1f);
    float o2 = leaky(a2 * inv + cb.z, 0.1f);
    float o3 = leaky(a3 * inv + cb.w, 0.1f);
    float sc = scales[layer];
    float wl = wsm[layer];
    size_t base = (size_t)wv * 256 + lane * 4;
    float4 res = *(const float4*)(h + base);
    float4 hn;
    hn.x = fmaf(sc, o0, res.x); hn.y = fmaf(sc, o1, res.y);
    hn.z = fmaf(sc, o2, res.z); hn.w = fmaf(sc, o3, res.w);
    *(float4*)(h + base) = hn;
    float4 hs;
    if (layer == 0) {
        hs.x = wl * hn.x; hs.y = wl * hn.y; hs.z = wl * hn.z; hs.w = wl * hn.w;
    } else {
        hs = *(const float4*)(hsum + base);
        hs.x = fmaf(wl, hn.x, hs.x); hs.y = fmaf(wl, hn.y, hs.y);
        hs.z = fmaf(wl, hn.z, hs.z); hs.w = fmaf(wl, hn.w, hs.w);
    }
    *(float4*)(hsum + base) = hs;
}

// ---------------- final y2[N,128] @ h3_w[128,1] + h3_b ----------------
__global__ __launch_bounds__(256) void out_k(const float* __restrict__ y2,
                                             const float* __restrict__ w,
                                             const float* __restrict__ b,
                                             float* __restrict__ out, int N)
{
    int wv = blockIdx.x * 4 + (threadIdx.x >> 6);
    if (wv >= N) return;
    int lane = threadIdx.x & 63;
    float2 v = *(const float2*)(y2 + (size_t)wv * 128 + lane * 2);
    float2 ww = *(const float2*)(w + lane * 2);
    float pm = v.x * ww.x + v.y * ww.y;
#pragma unroll
    for (int off = 1; off < 64; off <<= 1) pm += __shfl_xor(pm, off);
    if (lane == 0) out[wv] = pm + b[0];
}

extern "C" void kernel_launch(void* const* d_in, const int* in_sizes, int n_in,
                              void* d_out, int out_size, void* d_ws, size_t ws_size,
                              hipStream_t stream)
{
    const int N = NN, E = EE, Etot = EE + NN;
    const float* x      = (const float*)d_in[0];
    const int*   ei     = (const int*)  d_in[1];
    const float* win_w  = (const float*)d_in[2];
    const float* win_b  = (const float*)d_in[3];
    const float* bn1_g  = (const float*)d_in[4];
    const float* bn1_b  = (const float*)d_in[5];
    const float* ln_g   = (const float*)d_in[6];
    const float* ln_b   = (const float*)d_in[7];
    const float* Wl     = (const float*)d_in[8];
    const float* bl     = (const float*)d_in[9];
    const float* Wr     = (const float*)d_in[10];
    const float* br     = (const float*)d_in[11];
    const float* att    = (const float*)d_in[12];
    const float* conv_b = (const float*)d_in[13];
    const float* scales = (const float*)d_in[14];
    const float* sw     = (const float*)d_in[15];
    const float* h1_w   = (const float*)d_in[16];
    const float* h1_b   = (const float*)d_in[17];
    const float* bn2_g  = (const float*)d_in[18];
    const float* bn2_b  = (const float*)d_in[19];
    const float* h2_w   = (const float*)d_in[20];
    const float* h2_b   = (const float*)d_in[21];
    const float* h3_w   = (const float*)d_in[22];
    const float* h3_b   = (const float*)d_in[23];

    // workspace carve (~158 MB)
    char* p = (char*)d_ws;
    auto take = [&](size_t b) -> char* {
        char* q = p; p += (b + 255) & ~(size_t)255; return q;
    };
    float* h             = (float*)take((size_t)N * 256 * 4);
    float* hsum          = (float*)take((size_t)N * 256 * 4);
    unsigned short* xl   = (unsigned short*)take((size_t)N * 256 * 2);
    unsigned short* xr   = (unsigned short*)take((size_t)N * 256 * 2);
    float* mu            = (float*)take((size_t)N * 4);
    float* rsig          = (float*)take((size_t)N * 4);
    float* wsm           = (float*)take(256);
    int*   offsets       = (int*)take((size_t)(N + 1) * 4);
    int*   cursor        = (int*)take((size_t)N * 4);
    int*   eidx          = (int*)take((size_t)Etot * 4);
    float* y1 = h;             // h free after last layer
    float* y2 = (float*)xl;    // xl region free after last layer (25.6MB needed, 51.2MB avail)

    const int EB = (Etot + 255) / 256;
    const int NB = (N + 3) / 4;          // 12500

    // CSR build (per call; deterministic)
    hipMemsetAsync(cursor, 0, (size_t)N * 4, stream);
    hist_k<<<EB, 256, 0, stream>>>(ei, E, N, cursor);
    scan_k<<<1, 1024, 0, stream>>>(cursor, offsets, N, Etot);
    hipMemcpyAsync(cursor, offsets, (size_t)N * 4, hipMemcpyDeviceToDevice, stream);
    scatter_k<<<EB, 256, 0, stream>>>(ei, E, N, cursor, eidx);
    softmax6_k<<<1, 64, 0, stream>>>(sw, wsm);

    dim3 g2d((N + BM - 1) / BM, 2);  // 391 x 2
    // h = leaky(bn1(x @ win_w + win_b), 0.1)
    gemm_k<1, false, false><<<g2d, 256, 0, stream>>>(
        x, win_w, win_b, nullptr, nullptr, nullptr, nullptr, bn1_g, bn1_b, h, N, 128, 256);

    for (int l = 0; l < LL; ++l) {
        ln_stats_k<<<NB, 256, 0, stream>>>(h, mu, rsig, N);
        gemm_k<0, true, true><<<g2d, 256, 0, stream>>>(
            h, Wl + (size_t)l * 65536, bl + l * 256, mu, rsig,
            ln_g + l * 256, ln_b + l * 256, nullptr, nullptr, xl, N, 256, 256);
        gemm_k<0, true, true><<<g2d, 256, 0, stream>>>(
            h, Wr + (size_t)l * 65536, br + l * 256, mu, rsig,
            ln_g + l * 256, ln_b + l * 256, nullptr, nullptr, xr, N, 256, 256);
        edge_k<<<NB, 256, 0, stream>>>(xl, xr, att + l * 256, conv_b + l * 256,
                                       offsets, eidx, h, hsum, wsm, scales, l, N);
    }

    // y1 = leaky(bn2(hsum @ h1_w + h1_b), 0.1)
    gemm_k<1, false, false><<<g2d, 256, 0, stream>>>(
        hsum, h1_w, h1_b, nullptr, nullptr, nullptr, nullptr, bn2_g, bn2_b, y1, N, 256, 256);
    // y2 = leaky(y1 @ h2_w + h2_b, 0.1)
    gemm_k<2, false, false><<<dim3((N + BM - 1) / BM, 1), 256, 0, stream>>>(
        y1, h2_w, h2_b, nullptr, nullptr, nullptr, nullptr, nullptr, nullptr, y2, N, 256, 128);
    // out = y2 @ h3_w + h3_b
    out_k<<<NB, 256, 0, stream>>>(y2, h3_w, h3_b, (float*)d_out, N);
}

// Round 2
// 1587.548 us; speedup vs baseline: 1.6177x; 1.6177x over previous
//
#include <hip/hip_runtime.h>

#define NN 50000
#define EE 800000
#define LL 6
constexpr float EPSF = 1e-5f;

typedef __bf16 bf16x8 __attribute__((ext_vector_type(8)));
typedef float f32x4 __attribute__((ext_vector_type(4)));
typedef unsigned short u16x8 __attribute__((ext_vector_type(8)));

__device__ __forceinline__ float bf2f(unsigned short u) {
    union { unsigned int i; float f; } v; v.i = ((unsigned int)u) << 16; return v.f;
}
__device__ __forceinline__ unsigned short f2bf(float f) {
    union { float f; unsigned int i; } v; v.f = f;
    unsigned int r = v.i + 0x7FFFu + ((v.i >> 16) & 1u);
    return (unsigned short)(r >> 16);
}
__device__ __forceinline__ float leaky(float v, float s) { return v > 0.f ? v : s * v; }

// ---------------- weight prep: fp32 [K][N] -> bf16 B^T [N][K] ----------------
__global__ __launch_bounds__(256) void cvt_t_k(const float* __restrict__ in,
                                               unsigned short* __restrict__ out,
                                               int K, int N)
{
    __shared__ float t[64][65];
    const int k0 = blockIdx.x * 64, n0 = blockIdx.y * 64;
    const int tid = threadIdx.x;
    {
        int kl = tid >> 2, np = (tid & 3) * 16;
        const float* ip = in + (size_t)(k0 + kl) * N + n0 + np;
        float4 a = *(const float4*)(ip + 0);
        float4 b = *(const float4*)(ip + 4);
        float4 c = *(const float4*)(ip + 8);
        float4 d = *(const float4*)(ip + 12);
        t[kl][np + 0] = a.x; t[kl][np + 1] = a.y; t[kl][np + 2] = a.z; t[kl][np + 3] = a.w;
        t[kl][np + 4] = b.x; t[kl][np + 5] = b.y; t[kl][np + 6] = b.z; t[kl][np + 7] = b.w;
        t[kl][np + 8] = c.x; t[kl][np + 9] = c.y; t[kl][np +10] = c.z; t[kl][np +11] = c.w;
        t[kl][np +12] = d.x; t[kl][np +13] = d.y; t[kl][np +14] = d.z; t[kl][np +15] = d.w;
    }
    __syncthreads();
    {
        int nl = tid >> 2, kp = (tid & 3) * 16;
        u16x8 o0, o1;
#pragma unroll
        for (int i = 0; i < 8; ++i) o0[i] = f2bf(t[kp + i][nl]);
#pragma unroll
        for (int i = 0; i < 8; ++i) o1[i] = f2bf(t[kp + 8 + i][nl]);
        unsigned short* op = out + (size_t)(n0 + nl) * K + k0 + kp;
        *(u16x8*)(op + 0) = o0;
        *(u16x8*)(op + 8) = o1;
    }
}

// ---------------- MFMA GEMM: C = act( LN(A) @ B + bias ) ----------------
// B supplied pre-transposed bf16 [N][K]. 128x128 tile, BK=32, 4 waves (each 64x64).
// MODE 0: +bias. MODE 1: +bias, *g/sqrt(1+eps)+b2, leaky 0.1. MODE 2: +bias, leaky 0.1.
constexpr int BM = 128, BN = 128, BK = 32;
constexpr int LDK = BK + 8;   // pad to 40 shorts (80B): uniform bank distribution

template<int MODE, bool LN, bool OUT_BF16>
__global__ __launch_bounds__(256) void gemm_mfma_k(
    const float* __restrict__ A, const unsigned short* __restrict__ Bt,
    const float* __restrict__ bias,
    const float* __restrict__ mu, const float* __restrict__ rsig,
    const float* __restrict__ lng, const float* __restrict__ lnb,
    const float* __restrict__ g2, const float* __restrict__ b2,
    void* __restrict__ Cv, int M, int K, int N)
{
    __shared__ unsigned short As[BM][LDK];
    __shared__ unsigned short Bs[BN][LDK];
    const int tid  = threadIdx.x;
    const int lane = tid & 63;
    const int wave = tid >> 6;
    const int bm = blockIdx.x * BM;
    const int bn = blockIdx.y * BN;
    const int wm = (wave & 1) * 64;
    const int wn = (wave >> 1) * 64;
    const int sr = tid >> 1;            // staging row 0..127
    const int sk = (tid & 1) * 16;      // staging k-offset 0/16
    const int mrow = lane & 15;
    const int kq   = (lane >> 4) * 8;

    f32x4 acc[4][4];
#pragma unroll
    for (int i = 0; i < 4; ++i)
#pragma unroll
        for (int j = 0; j < 4; ++j) acc[i][j] = (f32x4){0.f, 0.f, 0.f, 0.f};

    for (int k0 = 0; k0 < K; k0 += BK) {
        // ---- A stage: 16 fp32 -> LN -> bf16 ----
        {
            int gr = bm + sr;
            float va[16];
            if (gr < M) {
                const float* ap = A + (size_t)gr * K + k0 + sk;
                float4 v0 = *(const float4*)(ap + 0);
                float4 v1 = *(const float4*)(ap + 4);
                float4 v2 = *(const float4*)(ap + 8);
                float4 v3 = *(const float4*)(ap + 12);
                va[0]=v0.x; va[1]=v0.y; va[2]=v0.z; va[3]=v0.w;
                va[4]=v1.x; va[5]=v1.y; va[6]=v1.z; va[7]=v1.w;
                va[8]=v2.x; va[9]=v2.y; va[10]=v2.z; va[11]=v2.w;
                va[12]=v3.x; va[13]=v3.y; va[14]=v3.z; va[15]=v3.w;
                if constexpr (LN) {
                    float m = mu[gr], rs = rsig[gr];
                    const float* gp = lng + k0 + sk;
                    const float* bp = lnb + k0 + sk;
#pragma unroll
                    for (int i = 0; i < 16; ++i)
                        va[i] = (va[i] - m) * rs * gp[i] + bp[i];
                }
            } else {
#pragma unroll
                for (int i = 0; i < 16; ++i) va[i] = 0.f;
            }
            u16x8 lo, hi;
#pragma unroll
            for (int i = 0; i < 8; ++i) lo[i] = f2bf(va[i]);
#pragma unroll
            for (int i = 0; i < 8; ++i) hi[i] = f2bf(va[8 + i]);
            *(u16x8*)&As[sr][sk]     = lo;
            *(u16x8*)&As[sr][sk + 8] = hi;
        }
        // ---- B stage: bf16 copy (B^T rows contiguous in k) ----
        {
            const unsigned short* bp = Bt + (size_t)(bn + sr) * K + k0 + sk;
            u16x8 b0 = *(const u16x8*)(bp + 0);
            u16x8 b1 = *(const u16x8*)(bp + 8);
            *(u16x8*)&Bs[sr][sk]     = b0;
            *(u16x8*)&Bs[sr][sk + 8] = b1;
        }
        __syncthreads();
        bf16x8 af[4], bf[4];
#pragma unroll
        for (int i = 0; i < 4; ++i)
            af[i] = *(const bf16x8*)&As[wm + 16 * i + mrow][kq];
#pragma unroll
        for (int j = 0; j < 4; ++j)
            bf[j] = *(const bf16x8*)&Bs[wn + 16 * j + mrow][kq];
#pragma unroll
        for (int i = 0; i < 4; ++i)
#pragma unroll
            for (int j = 0; j < 4; ++j)
                acc[i][j] = __builtin_amdgcn_mfma_f32_16x16x32_bf16(af[i], bf[j], acc[i][j], 0, 0, 0);
        __syncthreads();
    }

    // ---- epilogue ----
    const float inv_s = 0.9999950000374997f; // 1/sqrt(1+1e-5)
    const int rq = (lane >> 4) * 4;
    float bsj[4], gj[4], bbj[4];
#pragma unroll
    for (int j = 0; j < 4; ++j) {
        int c = bn + wn + 16 * j + mrow;
        bsj[j] = bias[c];
        if constexpr (MODE == 1) { gj[j] = g2[c]; bbj[j] = b2[c]; }
    }
#pragma unroll
    for (int i = 0; i < 4; ++i) {
#pragma unroll
        for (int r = 0; r < 4; ++r) {
            int grow = bm + wm + 16 * i + rq + r;
            if (grow >= M) continue;
#pragma unroll
            for (int j = 0; j < 4; ++j) {
                int c = bn + wn + 16 * j + mrow;
                float v = acc[i][j][r] + bsj[j];
                if constexpr (MODE == 1) v = leaky(v * inv_s * gj[j] + bbj[j], 0.1f);
                else if constexpr (MODE == 2) v = leaky(v, 0.1f);
                if constexpr (OUT_BF16)
                    ((unsigned short*)Cv)[(size_t)grow * N + c] = f2bf(v);
                else
                    ((float*)Cv)[(size_t)grow * N + c] = v;
            }
        }
    }
}

// ---------------- LayerNorm row stats (wave per row of 256) ----------------
__global__ __launch_bounds__(256) void ln_stats_k(const float* __restrict__ h,
                                                  float* __restrict__ mu,
                                                  float* __restrict__ rsig, int N)
{
    int wv = blockIdx.x * 4 + (threadIdx.x >> 6);
    if (wv >= N) return;
    int lane = threadIdx.x & 63;
    float4 v = *(const float4*)(h + (size_t)wv * 256 + lane * 4);
    float s = v.x + v.y + v.z + v.w;
#pragma unroll
    for (int off = 1; off < 64; off <<= 1) s += __shfl_xor(s, off);
    float m = s * (1.f / 256.f);
    float d0 = v.x - m, d1 = v.y - m, d2 = v.z - m, d3 = v.w - m;
    float q = d0 * d0 + d1 * d1 + d2 * d2 + d3 * d3;
#pragma unroll
    for (int off = 1; off < 64; off <<= 1) q += __shfl_xor(q, off);
    if (lane == 0) { mu[wv] = m; rsig[wv] = rsqrtf(q * (1.f / 256.f) + EPSF); }
}

// ---------------- CSR build ----------------
__global__ __launch_bounds__(256) void hist_k(const int* __restrict__ ei, int E, int N,
                                              int* __restrict__ counts)
{
    int e = blockIdx.x * 256 + threadIdx.x;
    int Etot = E + N;
    if (e >= Etot) return;
    int d = (e < E) ? ei[E + e] : (e - E);
    atomicAdd(&counts[d], 1);
}

__global__ __launch_bounds__(1024) void scan_k(const int* __restrict__ counts,
                                               int* __restrict__ offsets, int N, int Etot)
{
    __shared__ int sm[1024];
    __shared__ int carry;
    if (threadIdx.x == 0) carry = 0;
    __syncthreads();
    for (int base = 0; base < N; base += 1024) {
        int i = base + threadIdx.x;
        int v = (i < N) ? counts[i] : 0;
        sm[threadIdx.x] = v;
        __syncthreads();
        for (int off = 1; off < 1024; off <<= 1) {
            int t = (threadIdx.x >= off) ? sm[threadIdx.x - off] : 0;
            __syncthreads();
            sm[threadIdx.x] += t;
            __syncthreads();
        }
        if (i < N) offsets[i] = carry + sm[threadIdx.x] - v;
        __syncthreads();
        if (threadIdx.x == 0) carry += sm[1023];
        __syncthreads();
    }
    if (threadIdx.x == 0) offsets[N] = Etot;
}

__global__ __launch_bounds__(256) void scatter_k(const int* __restrict__ ei, int E, int N,
                                                 int* __restrict__ cursor, int* __restrict__ eidx)
{
    int e = blockIdx.x * 256 + threadIdx.x;
    int Etot = E + N;
    if (e >= Etot) return;
    int s, d;
    if (e < E) { s = ei[e]; d = ei[E + e]; }
    else       { s = e - E; d = s; }
    int pos = atomicAdd(&cursor[d], 1);
    eidx[pos] = s;
}

__global__ void softmax6_k(const float* __restrict__ sw, float* __restrict__ w)
{
    if (threadIdx.x == 0 && blockIdx.x == 0) {
        float m = -1e30f;
        for (int l = 0; l < LL; ++l) m = fmaxf(m, sw[l]);
        float e[LL]; float s = 0.f;
        for (int l = 0; l < LL; ++l) { e[l] = __expf(sw[l] - m); s += e[l]; }
        for (int l = 0; l < LL; ++l) w[l] = e[l] / s;
    }
}

// ---------------- Edge aggregation + fused LN stats for next layer ----------------
__global__ __launch_bounds__(256) void edge_k(
    const unsigned short* __restrict__ xl, const unsigned short* __restrict__ xr,
    const float* __restrict__ att, const float* __restrict__ convb,
    const int* __restrict__ offsets, const int* __restrict__ eidx,
    float* __restrict__ h, float* __restrict__ hsum,
    float* __restrict__ mu, float* __restrict__ rsig,
    const float* __restrict__ wsm, const float* __restrict__ scales,
    int layer, int N)
{
    int wv = blockIdx.x * 4 + (threadIdx.x >> 6);
    if (wv >= N) return;
    int lane = threadIdx.x & 63;
    float4 attv = *(const float4*)(att + lane * 4);
    ushort4 xru = *(const ushort4*)(xr + (size_t)wv * 256 + lane * 4);
    float xr0 = bf2f(xru.x), xr1 = bf2f(xru.y), xr2 = bf2f(xru.z), xr3 = bf2f(xru.w);
    int e0 = offsets[wv], e1 = offsets[wv + 1];
    float den = 0.f, a0 = 0.f, a1 = 0.f, a2 = 0.f, a3 = 0.f;
    for (int e = e0; e < e1; ++e) {
        int s = eidx[e];
        ushort4 xu = *(const ushort4*)(xl + (size_t)s * 256 + lane * 4);
        float x0 = bf2f(xu.x), x1 = bf2f(xu.y), x2 = bf2f(xu.z), x3 = bf2f(xu.w);
        float v0 = x0 + xr0; v0 = v0 > 0.f ? v0 : 0.2f * v0;
        float v1 = x1 + xr1; v1 = v1 > 0.f ? v1 : 0.2f * v1;
        float v2 = x2 + xr2; v2 = v2 > 0.f ? v2 : 0.2f * v2;
        float v3 = x3 + xr3; v3 = v3 > 0.f ? v3 : 0.2f * v3;
        float pm = attv.x * v0 + attv.y * v1 + attv.z * v2 + attv.w * v3;
        pm += __shfl_xor(pm, 1);
        pm += __shfl_xor(pm, 2);
        pm += __shfl_xor(pm, 4);
        float ex = __expf(pm);
        den += ex;
        a0 = fmaf(x0, ex, a0); a1 = fmaf(x1, ex, a1);
        a2 = fmaf(x2, ex, a2); a3 = fmaf(x3, ex, a3);
    }
    float inv = 1.f / den;
    float4 cb = *(const float4*)(convb + lane * 4);
    float o0 = leaky(a0 * inv + cb.x, 0.1f);
    float o1 = leaky(a1 * inv + cb.y, 0.1f);
    float o2 = leaky(a2 * inv + cb.z, 0.1f);
    float o3 = leaky(a3 * inv + cb.w, 0.1f);
    float sc = scales[layer];
    float wl = wsm[layer];
    size_t base = (size_t)wv * 256 + lane * 4;
    float4 res = *(const float4*)(h + base);
    float4 hn;
    hn.x = fmaf(sc, o0, res.x); hn.y = fmaf(sc, o1, res.y);
    hn.z = fmaf(sc, o2, res.z); hn.w = fmaf(sc, o3, res.w);
    *(float4*)(h + base) = hn;
    float4 hs;
    if (layer == 0) {
        hs.x = wl * hn.x; hs.y = wl * hn.y; hs.z = wl * hn.z; hs.w = wl * hn.w;
    } else {
        hs = *(const float4*)(hsum + base);
        hs.x = fmaf(wl, hn.x, hs.x); hs.y = fmaf(wl, hn.y, hs.y);
        hs.z = fmaf(wl, hn.z, hs.z); hs.w = fmaf(wl, hn.w, hs.w);
    }
    *(float4*)(hsum + base) = hs;
    // fused LN stats of hn (used by next layer's GEMMs)
    float s1 = hn.x + hn.y + hn.z + hn.w;
#pragma unroll
    for (int off = 1; off < 64; off <<= 1) s1 += __shfl_xor(s1, off);
    float m = s1 * (1.f / 256.f);
    float d0 = hn.x - m, d1 = hn.y - m, d2 = hn.z - m, d3 = hn.w - m;
    float q = d0 * d0 + d1 * d1 + d2 * d2 + d3 * d3;
#pragma unroll
    for (int off = 1; off < 64; off <<= 1) q += __shfl_xor(q, off);
    if (lane == 0) { mu[wv] = m; rsig[wv] = rsqrtf(q * (1.f / 256.f) + EPSF); }
}

// ---------------- final y2[N,128] @ h3_w[128,1] + h3_b ----------------
__global__ __launch_bounds__(256) void out_k(const float* __restrict__ y2,
                                             const float* __restrict__ w,
                                             const float* __restrict__ b,
                                             float* __restrict__ out, int N)
{
    int wv = blockIdx.x * 4 + (threadIdx.x >> 6);
    if (wv >= N) return;
    int lane = threadIdx.x & 63;
    float2 v = *(const float2*)(y2 + (size_t)wv * 128 + lane * 2);
    float2 ww = *(const float2*)(w + lane * 2);
    float pm = v.x * ww.x + v.y * ww.y;
#pragma unroll
    for (int off = 1; off < 64; off <<= 1) pm += __shfl_xor(pm, off);
    if (lane == 0) out[wv] = pm + b[0];
}

extern "C" void kernel_launch(void* const* d_in, const int* in_sizes, int n_in,
                              void* d_out, int out_size, void* d_ws, size_t ws_size,
                              hipStream_t stream)
{
    const int N = NN, E = EE, Etot = EE + NN;
    const float* x      = (const float*)d_in[0];
    const int*   ei     = (const int*)  d_in[1];
    const float* win_w  = (const float*)d_in[2];
    const float* win_b  = (const float*)d_in[3];
    const float* bn1_g  = (const float*)d_in[4];
    const float* bn1_b  = (const float*)d_in[5];
    const float* ln_g   = (const float*)d_in[6];
    const float* ln_b   = (const float*)d_in[7];
    const float* Wl     = (const float*)d_in[8];
    const float* bl     = (const float*)d_in[9];
    const float* Wr     = (const float*)d_in[10];
    const float* br     = (const float*)d_in[11];
    const float* att    = (const float*)d_in[12];
    const float* conv_b = (const float*)d_in[13];
    const float* scales = (const float*)d_in[14];
    const float* sw     = (const float*)d_in[15];
    const float* h1_w   = (const float*)d_in[16];
    const float* h1_b   = (const float*)d_in[17];
    const float* bn2_g  = (const float*)d_in[18];
    const float* bn2_b  = (const float*)d_in[19];
    const float* h2_w   = (const float*)d_in[20];
    const float* h2_b   = (const float*)d_in[21];
    const float* h3_w   = (const float*)d_in[22];
    const float* h3_b   = (const float*)d_in[23];

    // workspace carve (~160 MB)
    char* p = (char*)d_ws;
    auto take = [&](size_t b) -> char* {
        char* q = p; p += (b + 255) & ~(size_t)255; return q;
    };
    float* h             = (float*)take((size_t)N * 256 * 4);
    float* hsum          = (float*)take((size_t)N * 256 * 4);
    unsigned short* xl   = (unsigned short*)take((size_t)N * 256 * 2);
    unsigned short* xr   = (unsigned short*)take((size_t)N * 256 * 2);
    float* mu            = (float*)take((size_t)N * 4);
    float* rsig          = (float*)take((size_t)N * 4);
    float* wsm           = (float*)take(256);
    int*   offsets       = (int*)take((size_t)(N + 1) * 4);
    int*   cursor        = (int*)take((size_t)N * 4);
    int*   eidx          = (int*)take((size_t)Etot * 4);
    unsigned short* winT = (unsigned short*)take((size_t)128 * 256 * 2);
    unsigned short* WlT  = (unsigned short*)take((size_t)LL * 256 * 256 * 2);
    unsigned short* WrT  = (unsigned short*)take((size_t)LL * 256 * 256 * 2);
    unsigned short* h1T  = (unsigned short*)take((size_t)256 * 256 * 2);
    unsigned short* h2T  = (unsigned short*)take((size_t)256 * 128 * 2);
    float* y1 = h;             // h free after last layer
    float* y2 = (float*)xl;    // xl region free after last layer

    const int EB = (Etot + 255) / 256;
    const int NB = (N + 3) / 4;          // 12500

    // CSR build
    hipMemsetAsync(cursor, 0, (size_t)N * 4, stream);
    hist_k<<<EB, 256, 0, stream>>>(ei, E, N, cursor);
    scan_k<<<1, 1024, 0, stream>>>(cursor, offsets, N, Etot);
    hipMemcpyAsync(cursor, offsets, (size_t)N * 4, hipMemcpyDeviceToDevice, stream);
    scatter_k<<<EB, 256, 0, stream>>>(ei, E, N, cursor, eidx);
    softmax6_k<<<1, 64, 0, stream>>>(sw, wsm);

    // weight prep: convert + transpose to bf16 [N][K]
    cvt_t_k<<<dim3(2, 4), 256, 0, stream>>>(win_w, winT, 128, 256);
    for (int l = 0; l < LL; ++l) {
        cvt_t_k<<<dim3(4, 4), 256, 0, stream>>>(Wl + (size_t)l * 65536, WlT + (size_t)l * 65536, 256, 256);
        cvt_t_k<<<dim3(4, 4), 256, 0, stream>>>(Wr + (size_t)l * 65536, WrT + (size_t)l * 65536, 256, 256);
    }
    cvt_t_k<<<dim3(4, 4), 256, 0, stream>>>(h1_w, h1T, 256, 256);
    cvt_t_k<<<dim3(4, 2), 256, 0, stream>>>(h2_w, h2T, 256, 128);

    dim3 g2d((N + BM - 1) / BM, 2);  // 391 x 2

    // h = leaky(bn1(x @ win_w + win_b), 0.1)
    gemm_mfma_k<1, false, false><<<g2d, 256, 0, stream>>>(
        x, winT, win_b, nullptr, nullptr, nullptr, nullptr, bn1_g, bn1_b, h, N, 128, 256);
    ln_stats_k<<<NB, 256, 0, stream>>>(h, mu, rsig, N);

    for (int l = 0; l < LL; ++l) {
        gemm_mfma_k<0, true, true><<<g2d, 256, 0, stream>>>(
            h, WlT + (size_t)l * 65536, bl + l * 256, mu, rsig,
            ln_g + l * 256, ln_b + l * 256, nullptr, nullptr, xl, N, 256, 256);
        gemm_mfma_k<0, true, true><<<g2d, 256, 0, stream>>>(
            h, WrT + (size_t)l * 65536, br + l * 256, mu, rsig,
            ln_g + l * 256, ln_b + l * 256, nullptr, nullptr, xr, N, 256, 256);
        edge_k<<<NB, 256, 0, stream>>>(xl, xr, att + l * 256, conv_b + l * 256,
                                       offsets, eidx, h, hsum, mu, rsig, wsm, scales, l, N);
    }

    // y1 = leaky(bn2(hsum @ h1_w + h1_b), 0.1)
    gemm_mfma_k<1, false, false><<<g2d, 256, 0, stream>>>(
        hsum, h1T, h1_b, nullptr, nullptr, nullptr, nullptr, bn2_g, bn2_b, y1, N, 256, 256);
    // y2 = leaky(y1 @ h2_w + h2_b, 0.1)
    gemm_mfma_k<2, false, false><<<dim3((N + BM - 1) / BM, 1), 256, 0, stream>>>(
        y1, h2T, h2_b, nullptr, nullptr, nullptr, nullptr, nullptr, nullptr, y2, N, 256, 128);
    // out = y2 @ h3_w + h3_b
    out_k<<<NB, 256, 0, stream>>>(y2, h3_w, h3_b, (float*)d_out, N);
}

// Round 3
// 1231.017 us; speedup vs baseline: 2.0863x; 1.2896x over previous
//
#include <hip/hip_runtime.h>

#define NN 50000
#define EE 800000
#define LL 6
constexpr float EPSF = 1e-5f;

typedef __bf16 bf16x8 __attribute__((ext_vector_type(8)));
typedef float f32x4 __attribute__((ext_vector_type(4)));
typedef unsigned short u16x8 __attribute__((ext_vector_type(8)));

__device__ __forceinline__ float bf2f(unsigned short u) {
    union { unsigned int i; float f; } v; v.i = ((unsigned int)u) << 16; return v.f;
}
__device__ __forceinline__ unsigned short f2bf(float f) {
    union { float f; unsigned int i; } v; v.f = f;
    unsigned int r = v.i + 0x7FFFu + ((v.i >> 16) & 1u);
    return (unsigned short)(r >> 16);
}
__device__ __forceinline__ float leaky(float v, float s) { return v > 0.f ? v : s * v; }

// ------- weight prep: fp32 [K][N] -> bf16 B^T [N][K], optional row-scale gamma[k] -------
__global__ __launch_bounds__(256) void cvt_t_k(const float* __restrict__ in,
                                               unsigned short* __restrict__ out,
                                               const float* __restrict__ gamma,
                                               int K, int N)
{
    __shared__ float t[64][65];
    const int k0 = blockIdx.x * 64, n0 = blockIdx.y * 64;
    const int tid = threadIdx.x;
    {
        int kl = tid >> 2, np = (tid & 3) * 16;
        const float* ip = in + (size_t)(k0 + kl) * N + n0 + np;
        float4 a = *(const float4*)(ip + 0);
        float4 b = *(const float4*)(ip + 4);
        float4 c = *(const float4*)(ip + 8);
        float4 d = *(const float4*)(ip + 12);
        t[kl][np + 0] = a.x; t[kl][np + 1] = a.y; t[kl][np + 2] = a.z; t[kl][np + 3] = a.w;
        t[kl][np + 4] = b.x; t[kl][np + 5] = b.y; t[kl][np + 6] = b.z; t[kl][np + 7] = b.w;
        t[kl][np + 8] = c.x; t[kl][np + 9] = c.y; t[kl][np +10] = c.z; t[kl][np +11] = c.w;
        t[kl][np +12] = d.x; t[kl][np +13] = d.y; t[kl][np +14] = d.z; t[kl][np +15] = d.w;
    }
    __syncthreads();
    {
        int nl = tid >> 2, kp = (tid & 3) * 16;
        float g[16];
#pragma unroll
        for (int i = 0; i < 16; ++i) g[i] = gamma ? gamma[k0 + kp + i] : 1.f;
        u16x8 o0, o1;
#pragma unroll
        for (int i = 0; i < 8; ++i) o0[i] = f2bf(t[kp + i][nl] * g[i]);
#pragma unroll
        for (int i = 0; i < 8; ++i) o1[i] = f2bf(t[kp + 8 + i][nl] * g[8 + i]);
        unsigned short* op = out + (size_t)(n0 + nl) * K + k0 + kp;
        *(u16x8*)(op + 0) = o0;
        *(u16x8*)(op + 8) = o1;
    }
}

// ------- bias fold: b'[n] = b[n] + sum_k lnb[k]*W[k][n], per layer & side -------
__global__ __launch_bounds__(256) void biasfold_k(const float* __restrict__ bl,
                                                  const float* __restrict__ br,
                                                  const float* __restrict__ lnb,
                                                  const float* __restrict__ Wl,
                                                  const float* __restrict__ Wr,
                                                  float* __restrict__ biasLR)
{
    int l = blockIdx.x, side = blockIdx.y, n = threadIdx.x;
    const float* W = side ? Wr : Wl;
    const float* b = side ? br : bl;
    const float* lb = lnb + l * 256;
    const float* Wp = W + (size_t)l * 65536;
    float acc = b[l * 256 + n];
    for (int k = 0; k < 256; ++k) acc = fmaf(lb[k], Wp[(size_t)k * 256 + n], acc);
    biasLR[l * 512 + side * 256 + n] = acc;
}

constexpr int BM = 128, BN = 128, BK = 32;
constexpr int LDK = BK + 8;

// ------- fused layer GEMM: xlr = normed(bf16) @ WlrT + biasLR, out bf16 [M][512] -------
__global__ __launch_bounds__(256) void gemm_lr_k(
    const unsigned short* __restrict__ A, const unsigned short* __restrict__ Bt,
    const float* __restrict__ bias, unsigned short* __restrict__ C,
    int M, int K, int N)
{
    __shared__ unsigned short As[BM][LDK];
    __shared__ unsigned short Bs[BN][LDK];
    const int tid  = threadIdx.x;
    const int lane = tid & 63;
    const int wave = tid >> 6;
    const int bm = blockIdx.x * BM;
    const int bn = blockIdx.y * BN;
    const int wm = (wave & 1) * 64;
    const int wn = (wave >> 1) * 64;
    const int sr = tid >> 1;
    const int sk = (tid & 1) * 16;
    const int mrow = lane & 15;
    const int kq   = (lane >> 4) * 8;

    f32x4 acc[4][4];
#pragma unroll
    for (int i = 0; i < 4; ++i)
#pragma unroll
        for (int j = 0; j < 4; ++j) acc[i][j] = (f32x4){0.f, 0.f, 0.f, 0.f};

    for (int k0 = 0; k0 < K; k0 += BK) {
        {
            int gr = bm + sr;
            u16x8 a0 = {}, a1 = {};
            if (gr < M) {
                const unsigned short* ap = A + (size_t)gr * K + k0 + sk;
                a0 = *(const u16x8*)(ap + 0);
                a1 = *(const u16x8*)(ap + 8);
            }
            *(u16x8*)&As[sr][sk]     = a0;
            *(u16x8*)&As[sr][sk + 8] = a1;
        }
        {
            const unsigned short* bp = Bt + (size_t)(bn + sr) * K + k0 + sk;
            u16x8 b0 = *(const u16x8*)(bp + 0);
            u16x8 b1 = *(const u16x8*)(bp + 8);
            *(u16x8*)&Bs[sr][sk]     = b0;
            *(u16x8*)&Bs[sr][sk + 8] = b1;
        }
        __syncthreads();
        bf16x8 af[4], bf[4];
#pragma unroll
        for (int i = 0; i < 4; ++i) af[i] = *(const bf16x8*)&As[wm + 16 * i + mrow][kq];
#pragma unroll
        for (int j = 0; j < 4; ++j) bf[j] = *(const bf16x8*)&Bs[wn + 16 * j + mrow][kq];
#pragma unroll
        for (int i = 0; i < 4; ++i)
#pragma unroll
            for (int j = 0; j < 4; ++j)
                acc[i][j] = __builtin_amdgcn_mfma_f32_16x16x32_bf16(af[i], bf[j], acc[i][j], 0, 0, 0);
        __syncthreads();
    }

    const int rq = (lane >> 4) * 4;
    float bsj[4];
#pragma unroll
    for (int j = 0; j < 4; ++j) bsj[j] = bias[bn + wn + 16 * j + mrow];
#pragma unroll
    for (int i = 0; i < 4; ++i)
#pragma unroll
        for (int r = 0; r < 4; ++r) {
            int grow = bm + wm + 16 * i + rq + r;
            if (grow >= M) continue;
#pragma unroll
            for (int j = 0; j < 4; ++j) {
                int c = bn + wn + 16 * j + mrow;
                C[(size_t)grow * N + c] = f2bf(acc[i][j][r] + bsj[j]);
            }
        }
}

// ------- fp32-A GEMM (entry / exit MLP): C = act(A @ B + bias) -------
// MODE 1: *g/sqrt(1+eps)+b2, leaky 0.1. MODE 2: leaky 0.1.
template<int MODE>
__global__ __launch_bounds__(256) void gemm_f32_k(
    const float* __restrict__ A, const unsigned short* __restrict__ Bt,
    const float* __restrict__ bias, const float* __restrict__ g2,
    const float* __restrict__ b2, float* __restrict__ C,
    int M, int K, int N)
{
    __shared__ unsigned short As[BM][LDK];
    __shared__ unsigned short Bs[BN][LDK];
    const int tid  = threadIdx.x;
    const int lane = tid & 63;
    const int wave = tid >> 6;
    const int bm = blockIdx.x * BM;
    const int bn = blockIdx.y * BN;
    const int wm = (wave & 1) * 64;
    const int wn = (wave >> 1) * 64;
    const int sr = tid >> 1;
    const int sk = (tid & 1) * 16;
    const int mrow = lane & 15;
    const int kq   = (lane >> 4) * 8;

    f32x4 acc[4][4];
#pragma unroll
    for (int i = 0; i < 4; ++i)
#pragma unroll
        for (int j = 0; j < 4; ++j) acc[i][j] = (f32x4){0.f, 0.f, 0.f, 0.f};

    for (int k0 = 0; k0 < K; k0 += BK) {
        {
            int gr = bm + sr;
            u16x8 lo = {}, hi = {};
            if (gr < M) {
                const float* ap = A + (size_t)gr * K + k0 + sk;
                float4 v0 = *(const float4*)(ap + 0);
                float4 v1 = *(const float4*)(ap + 4);
                float4 v2 = *(const float4*)(ap + 8);
                float4 v3 = *(const float4*)(ap + 12);
                lo[0]=f2bf(v0.x); lo[1]=f2bf(v0.y); lo[2]=f2bf(v0.z); lo[3]=f2bf(v0.w);
                lo[4]=f2bf(v1.x); lo[5]=f2bf(v1.y); lo[6]=f2bf(v1.z); lo[7]=f2bf(v1.w);
                hi[0]=f2bf(v2.x); hi[1]=f2bf(v2.y); hi[2]=f2bf(v2.z); hi[3]=f2bf(v2.w);
                hi[4]=f2bf(v3.x); hi[5]=f2bf(v3.y); hi[6]=f2bf(v3.z); hi[7]=f2bf(v3.w);
            }
            *(u16x8*)&As[sr][sk]     = lo;
            *(u16x8*)&As[sr][sk + 8] = hi;
        }
        {
            const unsigned short* bp = Bt + (size_t)(bn + sr) * K + k0 + sk;
            u16x8 b0 = *(const u16x8*)(bp + 0);
            u16x8 b1 = *(const u16x8*)(bp + 8);
            *(u16x8*)&Bs[sr][sk]     = b0;
            *(u16x8*)&Bs[sr][sk + 8] = b1;
        }
        __syncthreads();
        bf16x8 af[4], bf[4];
#pragma unroll
        for (int i = 0; i < 4; ++i) af[i] = *(const bf16x8*)&As[wm + 16 * i + mrow][kq];
#pragma unroll
        for (int j = 0; j < 4; ++j) bf[j] = *(const bf16x8*)&Bs[wn + 16 * j + mrow][kq];
#pragma unroll
        for (int i = 0; i < 4; ++i)
#pragma unroll
            for (int j = 0; j < 4; ++j)
                acc[i][j] = __builtin_amdgcn_mfma_f32_16x16x32_bf16(af[i], bf[j], acc[i][j], 0, 0, 0);
        __syncthreads();
    }

    const float inv_s = 0.9999950000374997f;
    const int rq = (lane >> 4) * 4;
    float bsj[4], gj[4], bbj[4];
#pragma unroll
    for (int j = 0; j < 4; ++j) {
        int c = bn + wn + 16 * j + mrow;
        bsj[j] = bias[c];
        if constexpr (MODE == 1) { gj[j] = g2[c]; bbj[j] = b2[c]; }
    }
#pragma unroll
    for (int i = 0; i < 4; ++i)
#pragma unroll
        for (int r = 0; r < 4; ++r) {
            int grow = bm + wm + 16 * i + rq + r;
            if (grow >= M) continue;
#pragma unroll
            for (int j = 0; j < 4; ++j) {
                int c = bn + wn + 16 * j + mrow;
                float v = acc[i][j][r] + bsj[j];
                if constexpr (MODE == 1) v = leaky(v * inv_s * gj[j] + bbj[j], 0.1f);
                else v = leaky(v, 0.1f);
                C[(size_t)grow * N + c] = v;
            }
        }
}

// ------- entry LN: normed = (h - mu) * rsig, bf16 -------
__global__ __launch_bounds__(256) void ln_norm_k(const float* __restrict__ h,
                                                 unsigned short* __restrict__ normed, int N)
{
    int wv = blockIdx.x * 4 + (threadIdx.x >> 6);
    if (wv >= N) return;
    int lane = threadIdx.x & 63;
    float4 v = *(const float4*)(h + (size_t)wv * 256 + lane * 4);
    float s = v.x + v.y + v.z + v.w;
#pragma unroll
    for (int off = 1; off < 64; off <<= 1) s += __shfl_xor(s, off);
    float m = s * (1.f / 256.f);
    float d0 = v.x - m, d1 = v.y - m, d2 = v.z - m, d3 = v.w - m;
    float q = d0 * d0 + d1 * d1 + d2 * d2 + d3 * d3;
#pragma unroll
    for (int off = 1; off < 64; off <<= 1) q += __shfl_xor(q, off);
    float rs = rsqrtf(q * (1.f / 256.f) + EPSF);
    ushort4 o;
    o.x = f2bf(d0 * rs); o.y = f2bf(d1 * rs); o.z = f2bf(d2 * rs); o.w = f2bf(d3 * rs);
    *(ushort4*)(normed + (size_t)wv * 256 + lane * 4) = o;
}

// ---------------- CSR build ----------------
__global__ __launch_bounds__(256) void hist_k(const int* __restrict__ ei, int E, int N,
                                              int* __restrict__ counts)
{
    int e = blockIdx.x * 256 + threadIdx.x;
    int Etot = E + N;
    if (e >= Etot) return;
    int d = (e < E) ? ei[E + e] : (e - E);
    atomicAdd(&counts[d], 1);
}

__global__ __launch_bounds__(1024) void scan_k(const int* __restrict__ counts,
                                               int* __restrict__ offsets, int N, int Etot)
{
    __shared__ int sm[1024];
    __shared__ int carry;
    if (threadIdx.x == 0) carry = 0;
    __syncthreads();
    for (int base = 0; base < N; base += 1024) {
        int i = base + threadIdx.x;
        int v = (i < N) ? counts[i] : 0;
        sm[threadIdx.x] = v;
        __syncthreads();
        for (int off = 1; off < 1024; off <<= 1) {
            int t = (threadIdx.x >= off) ? sm[threadIdx.x - off] : 0;
            __syncthreads();
            sm[threadIdx.x] += t;
            __syncthreads();
        }
        if (i < N) offsets[i] = carry + sm[threadIdx.x] - v;
        __syncthreads();
        if (threadIdx.x == 0) carry += sm[1023];
        __syncthreads();
    }
    if (threadIdx.x == 0) offsets[N] = Etot;
}

__global__ __launch_bounds__(256) void scatter_k(const int* __restrict__ ei, int E, int N,
                                                 int* __restrict__ cursor, int* __restrict__ eidx)
{
    int e = blockIdx.x * 256 + threadIdx.x;
    int Etot = E + N;
    if (e >= Etot) return;
    int s, d;
    if (e < E) { s = ei[e]; d = ei[E + e]; }
    else       { s = e - E; d = s; }
    int pos = atomicAdd(&cursor[d], 1);
    eidx[pos] = s;
}

__global__ void softmax6_k(const float* __restrict__ sw, float* __restrict__ w)
{
    if (threadIdx.x == 0 && blockIdx.x == 0) {
        float m = -1e30f;
        for (int l = 0; l < LL; ++l) m = fmaxf(m, sw[l]);
        float e[LL]; float s = 0.f;
        for (int l = 0; l < LL; ++l) { e[l] = __expf(sw[l] - m); s += e[l]; }
        for (int l = 0; l < LL; ++l) w[l] = e[l] / s;
    }
}

// ------- Edge aggregation: wave per node, 2 edge slots (32 lanes / 8 ch each) -------
__global__ __launch_bounds__(256) void edge_k(
    const unsigned short* __restrict__ xlr,
    const float* __restrict__ att, const float* __restrict__ convb,
    const int* __restrict__ offsets, const int* __restrict__ eidx,
    float* __restrict__ h, float* __restrict__ hsum,
    unsigned short* __restrict__ normed,
    const float* __restrict__ wsm, const float* __restrict__ scales,
    int layer, int N)
{
    int wv = blockIdx.x * 4 + (threadIdx.x >> 6);
    if (wv >= N) return;
    int lane = threadIdx.x & 63;
    int hl = lane & 31, slot = lane >> 5;
    int c8 = hl * 8;

    float atv[8], xrv[8];
    *(float4*)&atv[0] = *(const float4*)(att + c8);
    *(float4*)&atv[4] = *(const float4*)(att + c8 + 4);
    {
        u16x8 xu = *(const u16x8*)(xlr + (size_t)wv * 512 + 256 + c8);
#pragma unroll
        for (int j = 0; j < 8; ++j) xrv[j] = bf2f(xu[j]);
    }
    int e0 = offsets[wv], e1 = offsets[wv + 1];
    float den = 0.f;
    float a[8];
#pragma unroll
    for (int j = 0; j < 8; ++j) a[j] = 0.f;

    for (int e = e0 + slot; e < e1; e += 2) {
        int s = eidx[e];
        u16x8 xu = *(const u16x8*)(xlr + (size_t)s * 512 + c8);
        float xv[8], pm = 0.f;
#pragma unroll
        for (int j = 0; j < 8; ++j) {
            xv[j] = bf2f(xu[j]);
            float v = xv[j] + xrv[j];
            v = v > 0.f ? v : 0.2f * v;
            pm = fmaf(atv[j], v, pm);
        }
        pm += __shfl_xor(pm, 1);
        pm += __shfl_xor(pm, 2);
        float ex = __expf(pm);
        den += ex;
#pragma unroll
        for (int j = 0; j < 8; ++j) a[j] = fmaf(xv[j], ex, a[j]);
    }
    den += __shfl_xor(den, 32);
#pragma unroll
    for (int j = 0; j < 8; ++j) a[j] += __shfl_xor(a[j], 32);
    if (slot) return;   // epilogue by lanes 0..31; shfls below stay within them

    float inv = 1.f / den;
    float cb[8], res[8], hn[8];
    *(float4*)&cb[0] = *(const float4*)(convb + c8);
    *(float4*)&cb[4] = *(const float4*)(convb + c8 + 4);
    size_t base = (size_t)wv * 256 + c8;
    *(float4*)&res[0] = *(const float4*)(h + base);
    *(float4*)&res[4] = *(const float4*)(h + base + 4);
    float sc = scales[layer], wl = wsm[layer];
#pragma unroll
    for (int j = 0; j < 8; ++j)
        hn[j] = fmaf(sc, leaky(fmaf(a[j], inv, cb[j]), 0.1f), res[j]);
    *(float4*)(h + base)     = *(float4*)&hn[0];
    *(float4*)(h + base + 4) = *(float4*)&hn[4];
    float hs[8];
    if (layer == 0) {
#pragma unroll
        for (int j = 0; j < 8; ++j) hs[j] = wl * hn[j];
    } else {
        *(float4*)&hs[0] = *(const float4*)(hsum + base);
        *(float4*)&hs[4] = *(const float4*)(hsum + base + 4);
#pragma unroll
        for (int j = 0; j < 8; ++j) hs[j] = fmaf(wl, hn[j], hs[j]);
    }
    *(float4*)(hsum + base)     = *(float4*)&hs[0];
    *(float4*)(hsum + base + 4) = *(float4*)&hs[4];

    float s1 = 0.f;
#pragma unroll
    for (int j = 0; j < 8; ++j) s1 += hn[j];
#pragma unroll
    for (int off = 1; off < 32; off <<= 1) s1 += __shfl_xor(s1, off);
    float m = s1 * (1.f / 256.f);
    float q = 0.f;
#pragma unroll
    for (int j = 0; j < 8; ++j) { float d = hn[j] - m; q = fmaf(d, d, q); }
#pragma unroll
    for (int off = 1; off < 32; off <<= 1) q += __shfl_xor(q, off);
    float rs = rsqrtf(q * (1.f / 256.f) + EPSF);
    u16x8 no;
#pragma unroll
    for (int j = 0; j < 8; ++j) no[j] = f2bf((hn[j] - m) * rs);
    *(u16x8*)(normed + base) = no;
}

// ---------------- final y2[N,128] @ h3_w[128,1] + h3_b ----------------
__global__ __launch_bounds__(256) void out_k(const float* __restrict__ y2,
                                             const float* __restrict__ w,
                                             const float* __restrict__ b,
                                             float* __restrict__ out, int N)
{
    int wv = blockIdx.x * 4 + (threadIdx.x >> 6);
    if (wv >= N) return;
    int lane = threadIdx.x & 63;
    float2 v = *(const float2*)(y2 + (size_t)wv * 128 + lane * 2);
    float2 ww = *(const float2*)(w + lane * 2);
    float pm = v.x * ww.x + v.y * ww.y;
#pragma unroll
    for (int off = 1; off < 64; off <<= 1) pm += __shfl_xor(pm, off);
    if (lane == 0) out[wv] = pm + b[0];
}

extern "C" void kernel_launch(void* const* d_in, const int* in_sizes, int n_in,
                              void* d_out, int out_size, void* d_ws, size_t ws_size,
                              hipStream_t stream)
{
    const int N = NN, E = EE, Etot = EE + NN;
    const float* x      = (const float*)d_in[0];
    const int*   ei     = (const int*)  d_in[1];
    const float* win_w  = (const float*)d_in[2];
    const float* win_b  = (const float*)d_in[3];
    const float* bn1_g  = (const float*)d_in[4];
    const float* bn1_b  = (const float*)d_in[5];
    const float* ln_g   = (const float*)d_in[6];
    const float* ln_b   = (const float*)d_in[7];
    const float* Wl     = (const float*)d_in[8];
    const float* bl     = (const float*)d_in[9];
    const float* Wr     = (const float*)d_in[10];
    const float* br     = (const float*)d_in[11];
    const float* att    = (const float*)d_in[12];
    const float* conv_b = (const float*)d_in[13];
    const float* scales = (const float*)d_in[14];
    const float* sw     = (const float*)d_in[15];
    const float* h1_w   = (const float*)d_in[16];
    const float* h1_b   = (const float*)d_in[17];
    const float* bn2_g  = (const float*)d_in[18];
    const float* bn2_b  = (const float*)d_in[19];
    const float* h2_w   = (const float*)d_in[20];
    const float* h2_b   = (const float*)d_in[21];
    const float* h3_w   = (const float*)d_in[22];
    const float* h3_b   = (const float*)d_in[23];

    char* p = (char*)d_ws;
    auto take = [&](size_t b) -> char* {
        char* q = p; p += (b + 255) & ~(size_t)255; return q;
    };
    float* h             = (float*)take((size_t)N * 256 * 4);
    float* hsum          = (float*)take((size_t)N * 256 * 4);
    unsigned short* norm = (unsigned short*)take((size_t)N * 256 * 2);
    unsigned short* xlr  = (unsigned short*)take((size_t)N * 512 * 2);
    float* wsm           = (float*)take(256);
    int*   offsets       = (int*)take((size_t)(N + 1) * 4);
    int*   cursor        = (int*)take((size_t)N * 4);
    int*   eidx          = (int*)take((size_t)Etot * 4);
    unsigned short* winT = (unsigned short*)take((size_t)128 * 256 * 2);
    unsigned short* WlrT = (unsigned short*)take((size_t)LL * 512 * 256 * 2);
    unsigned short* h1T  = (unsigned short*)take((size_t)256 * 256 * 2);
    unsigned short* h2T  = (unsigned short*)take((size_t)256 * 128 * 2);
    float* biasLR        = (float*)take((size_t)LL * 512 * 4);
    float* y1 = h;
    float* y2 = (float*)xlr;

    const int EB = (Etot + 255) / 256;
    const int NB = (N + 3) / 4;

    // CSR build
    hipMemsetAsync(cursor, 0, (size_t)N * 4, stream);
    hist_k<<<EB, 256, 0, stream>>>(ei, E, N, cursor);
    scan_k<<<1, 1024, 0, stream>>>(cursor, offsets, N, Etot);
    hipMemcpyAsync(cursor, offsets, (size_t)N * 4, hipMemcpyDeviceToDevice, stream);
    scatter_k<<<EB, 256, 0, stream>>>(ei, E, N, cursor, eidx);
    softmax6_k<<<1, 64, 0, stream>>>(sw, wsm);

    // weight prep: bf16 B^T with gamma folded into Wl/Wr rows; beta folded into bias
    cvt_t_k<<<dim3(2, 4), 256, 0, stream>>>(win_w, winT, nullptr, 128, 256);
    for (int l = 0; l < LL; ++l) {
        cvt_t_k<<<dim3(4, 4), 256, 0, stream>>>(Wl + (size_t)l * 65536,
            WlrT + (size_t)l * 131072, ln_g + l * 256, 256, 256);
        cvt_t_k<<<dim3(4, 4), 256, 0, stream>>>(Wr + (size_t)l * 65536,
            WlrT + (size_t)l * 131072 + 65536, ln_g + l * 256, 256, 256);
    }
    cvt_t_k<<<dim3(4, 4), 256, 0, stream>>>(h1_w, h1T, nullptr, 256, 256);
    cvt_t_k<<<dim3(4, 2), 256, 0, stream>>>(h2_w, h2T, nullptr, 256, 128);
    biasfold_k<<<dim3(LL, 2), 256, 0, stream>>>(bl, br, ln_b, Wl, Wr, biasLR);

    dim3 g2d((N + BM - 1) / BM, 2);   // 391 x 2
    dim3 g4d((N + BM - 1) / BM, 4);   // 391 x 4 (fused N=512)

    // entry: h = leaky(bn1(x @ win_w + win_b), 0.1); normed for layer 0
    gemm_f32_k<1><<<g2d, 256, 0, stream>>>(x, winT, win_b, bn1_g, bn1_b, h, N, 128, 256);
    ln_norm_k<<<NB, 256, 0, stream>>>(h, norm, N);

    for (int l = 0; l < LL; ++l) {
        gemm_lr_k<<<g4d, 256, 0, stream>>>(norm, WlrT + (size_t)l * 131072,
                                           biasLR + l * 512, xlr, N, 256, 512);
        edge_k<<<NB, 256, 0, stream>>>(xlr, att + l * 256, conv_b + l * 256,
                                       offsets, eidx, h, hsum, norm, wsm, scales, l, N);
    }

    // exit MLP
    gemm_f32_k<1><<<g2d, 256, 0, stream>>>(hsum, h1T, h1_b, bn2_g, bn2_b, y1, N, 256, 256);
    gemm_f32_k<2><<<dim3((N + BM - 1) / BM, 1), 256, 0, stream>>>(
        y1, h2T, h2_b, nullptr, nullptr, y2, N, 256, 128);
    out_k<<<NB, 256, 0, stream>>>(y2, h3_w, h3_b, (float*)d_out, N);
}

// Round 5
// 1202.888 us; speedup vs baseline: 2.1350x; 1.0234x over previous
//
#include <hip/hip_runtime.h>
#include <hip/hip_fp16.h>

#define NN 50000
#define EE 800000
#define LL 6
constexpr float EPSF = 1e-5f;

typedef _Float16 f16x8 __attribute__((ext_vector_type(8)));
typedef _Float16 f16x2 __attribute__((ext_vector_type(2)));
typedef float f32x4 __attribute__((ext_vector_type(4)));
typedef unsigned short u16x8 __attribute__((ext_vector_type(8)));

__device__ __forceinline__ float leaky(float v, float s) { return v > 0.f ? v : s * v; }

__device__ __forceinline__ __half2 u2h2(unsigned int u) {
    union { unsigned int x; __half2 h; } v; v.x = u; return v.h;
}
__device__ __forceinline__ unsigned int h22u(__half2 h) {
    union { __half2 h; unsigned int x; } v; v.h = h; return v.x;
}
__device__ __forceinline__ float dot2(__half2 a, __half2 b, float c) {
    union { __half2 h; f16x2 v; } ua, ub; ua.h = a; ub.h = b;
    return __builtin_amdgcn_fdot2(ua.v, ub.v, c, false);
}
// packed leaky 0.2: max(v, 0.2*v)  (v_pk_max_f16 + v_pk_mul_f16)
__device__ __forceinline__ __half2 lrelu2_02(__half2 v) {
    union U { __half2 h; f16x2 f; };
    U a; a.h = v;
    f16x2 b = a.f * (_Float16)0.2f;
    U r; r.f = __builtin_elementwise_max(a.f, b);
    return r.h;
}

// async global->LDS, 16B per lane; LDS dest = wave-uniform base + lane*16
#define GLD16(gp, sp) __builtin_amdgcn_global_load_lds( \
    (const __attribute__((address_space(1))) unsigned int*)(uintptr_t)(gp), \
    (__attribute__((address_space(3))) unsigned int*)(uintptr_t)(sp), 16, 0, 0)

// ------- weight prep: fp32 [K][N] -> fp16 B^T [N][K], optional row-scale gamma[k] -------
__global__ __launch_bounds__(256) void cvt_t_k(const float* __restrict__ in,
                                               __half* __restrict__ out,
                                               const float* __restrict__ gamma,
                                               int K, int N)
{
    __shared__ float t[64][65];
    const int k0 = blockIdx.x * 64, n0 = blockIdx.y * 64;
    const int tid = threadIdx.x;
    {
        int kl = tid >> 2, np = (tid & 3) * 16;
        const float* ip = in + (size_t)(k0 + kl) * N + n0 + np;
        float4 a = *(const float4*)(ip + 0);
        float4 b = *(const float4*)(ip + 4);
        float4 c = *(const float4*)(ip + 8);
        float4 d = *(const float4*)(ip + 12);
        t[kl][np + 0] = a.x; t[kl][np + 1] = a.y; t[kl][np + 2] = a.z; t[kl][np + 3] = a.w;
        t[kl][np + 4] = b.x; t[kl][np + 5] = b.y; t[kl][np + 6] = b.z; t[kl][np + 7] = b.w;
        t[kl][np + 8] = c.x; t[kl][np + 9] = c.y; t[kl][np +10] = c.z; t[kl][np +11] = c.w;
        t[kl][np +12] = d.x; t[kl][np +13] = d.y; t[kl][np +14] = d.z; t[kl][np +15] = d.w;
    }
    __syncthreads();
    {
        int nl = tid >> 2, kp = (tid & 3) * 16;
        u16x8 o0, o1;
#pragma unroll
        for (int i = 0; i < 8; ++i) {
            float g0 = gamma ? gamma[k0 + kp + i] : 1.f;
            float g1 = gamma ? gamma[k0 + kp + 8 + i] : 1.f;
            o0[i] = __half_as_ushort(__float2half(t[kp + i][nl] * g0));
            o1[i] = __half_as_ushort(__float2half(t[kp + 8 + i][nl] * g1));
        }
        unsigned short* op = (unsigned short*)out + (size_t)(n0 + nl) * K + k0 + kp;
        *(u16x8*)(op + 0) = o0;
        *(u16x8*)(op + 8) = o1;
    }
}

// ------- generic fp32 -> fp16 -------
__global__ __launch_bounds__(256) void cvt_h_k(const float* __restrict__ in,
                                               __half* __restrict__ out, int n)
{
    int i = blockIdx.x * 256 + threadIdx.x;
    if (i < n) out[i] = __float2half(in[i]);
}

// ------- bias fold: b'[n] = b[n] + sum_k lnb[k]*W[k][n] -------
__global__ __launch_bounds__(256) void biasfold_k(const float* __restrict__ bl,
                                                  const float* __restrict__ br,
                                                  const float* __restrict__ lnb,
                                                  const float* __restrict__ Wl,
                                                  const float* __restrict__ Wr,
                                                  float* __restrict__ biasLR)
{
    int l = blockIdx.x, side = blockIdx.y, n = threadIdx.x;
    const float* W = side ? Wr : Wl;
    const float* b = side ? br : bl;
    const float* lb = lnb + l * 256;
    const float* Wp = W + (size_t)l * 65536;
    float acc = b[l * 256 + n];
    for (int k = 0; k < 256; ++k) acc = fmaf(lb[k], Wp[(size_t)k * 256 + n], acc);
    biasLR[l * 512 + side * 256 + n] = acc;
}

// ------- fp16 MFMA GEMM, 128x128 tile, BK=64, global_load_lds staging, XOR swizzle ----
// A fp16 [M][K], Bt fp16 [N][K]. ACT 0: +bias. ACT 1: +bias,bn,leaky. ACT 2: +bias,leaky.
template<int ACT, bool OHALF>
__global__ __launch_bounds__(256) void gemm_h_k(
    const __half* __restrict__ A, const __half* __restrict__ Bt,
    const float* __restrict__ bias, const float* __restrict__ g2,
    const float* __restrict__ b2, void* __restrict__ Cv,
    int M, int K, int N)
{
    __shared__ _Float16 As[128 * 64];
    __shared__ _Float16 Bs[128 * 64];
    const int tid = threadIdx.x, lane = tid & 63, wave = tid >> 6;
    const int bm = blockIdx.x * 128, bn = blockIdx.y * 128;
    const int wm = (wave & 1) * 64, wn = (wave >> 1) * 64;
    const int mrow = lane & 15;
    // staging: lane covers sub-row sg (of 8) at source chunk sc (16B units, XOR swizzle)
    const int sg = lane >> 3;
    const int sc = (lane & 7) ^ sg;

    f32x4 acc[4][4];
#pragma unroll
    for (int i = 0; i < 4; ++i)
#pragma unroll
        for (int j = 0; j < 4; ++j) acc[i][j] = (f32x4){0.f, 0.f, 0.f, 0.f};

    for (int k0 = 0; k0 < K; k0 += 64) {
#pragma unroll
        for (int t = 0; t < 4; ++t) {
            int R = 32 * wave + 8 * t;
            int ar = bm + R + sg; if (ar >= M) ar = M - 1;
            GLD16(A + (size_t)ar * K + k0 + sc * 8, &As[R * 64]);
        }
#pragma unroll
        for (int t = 0; t < 4; ++t) {
            int R = 32 * wave + 8 * t;
            GLD16(Bt + (size_t)(bn + R + sg) * K + k0 + sc * 8, &Bs[R * 64]);
        }
        __syncthreads();
#pragma unroll
        for (int s2 = 0; s2 < 2; ++s2) {
            const int c = s2 * 4 + (lane >> 4);
            f16x8 af[4], bf[4];
#pragma unroll
            for (int i = 0; i < 4; ++i) {
                int r = wm + 16 * i + mrow;
                af[i] = *(const f16x8*)&As[r * 64 + ((c ^ (r & 7)) * 8)];
            }
#pragma unroll
            for (int j = 0; j < 4; ++j) {
                int r = wn + 16 * j + mrow;
                bf[j] = *(const f16x8*)&Bs[r * 64 + ((c ^ (r & 7)) * 8)];
            }
#pragma unroll
            for (int i = 0; i < 4; ++i)
#pragma unroll
                for (int j = 0; j < 4; ++j)
                    acc[i][j] = __builtin_amdgcn_mfma_f32_16x16x32_f16(af[i], bf[j], acc[i][j], 0, 0, 0);
        }
        __syncthreads();
    }

    const float inv_s = 0.9999950000374997f; // 1/sqrt(1+1e-5)
    const int rq = (lane >> 4) * 4;
    float bsj[4], gj[4], bbj[4];
#pragma unroll
    for (int j = 0; j < 4; ++j) {
        int cc = bn + wn + 16 * j + mrow;
        bsj[j] = bias[cc];
        if constexpr (ACT == 1) { gj[j] = g2[cc]; bbj[j] = b2[cc]; }
    }
#pragma unroll
    for (int i = 0; i < 4; ++i)
#pragma unroll
        for (int r = 0; r < 4; ++r) {
            int grow = bm + wm + 16 * i + rq + r;
            if (grow >= M) continue;
#pragma unroll
            for (int j = 0; j < 4; ++j) {
                int cc = bn + wn + 16 * j + mrow;
                float v = acc[i][j][r] + bsj[j];
                if constexpr (ACT == 1) v = leaky(v * inv_s * gj[j] + bbj[j], 0.1f);
                else if constexpr (ACT == 2) v = leaky(v, 0.1f);
                if constexpr (OHALF) ((__half*)Cv)[(size_t)grow * N + cc] = __float2half(v);
                else                 ((float*)Cv)[(size_t)grow * N + cc] = v;
            }
        }
}

// ------- entry LN: norm = (h - mu)*rsig -> fp16 -------
__global__ __launch_bounds__(256) void ln_norm_k(const float* __restrict__ h,
                                                 __half* __restrict__ normed, int N)
{
    int wv = blockIdx.x * 4 + (threadIdx.x >> 6);
    if (wv >= N) return;
    int lane = threadIdx.x & 63;
    float4 v = *(const float4*)(h + (size_t)wv * 256 + lane * 4);
    float s = v.x + v.y + v.z + v.w;
#pragma unroll
    for (int off = 1; off < 64; off <<= 1) s += __shfl_xor(s, off);
    float m = s * (1.f / 256.f);
    float d0 = v.x - m, d1 = v.y - m, d2 = v.z - m, d3 = v.w - m;
    float q = d0 * d0 + d1 * d1 + d2 * d2 + d3 * d3;
#pragma unroll
    for (int off = 1; off < 64; off <<= 1) q += __shfl_xor(q, off);
    float rs = rsqrtf(q * (1.f / 256.f) + EPSF);
    uint2 o;
    o.x = h22u(__floats2half2_rn(d0 * rs, d1 * rs));
    o.y = h22u(__floats2half2_rn(d2 * rs, d3 * rs));
    *(uint2*)((unsigned short*)normed + (size_t)wv * 256 + lane * 4) = o;
}

// ---------------- CSR build ----------------
__global__ __launch_bounds__(256) void hist_k(const int* __restrict__ ei, int E, int N,
                                              int* __restrict__ counts)
{
    int e = blockIdx.x * 256 + threadIdx.x;
    int Etot = E + N;
    if (e >= Etot) return;
    int d = (e < E) ? ei[E + e] : (e - E);
    atomicAdd(&counts[d], 1);
}

__global__ __launch_bounds__(1024) void scan_k(const int* __restrict__ counts,
                                               int* __restrict__ offsets, int N, int Etot)
{
    __shared__ int sm[1024];
    __shared__ int carry;
    if (threadIdx.x == 0) carry = 0;
    __syncthreads();
    for (int base = 0; base < N; base += 1024) {
        int i = base + threadIdx.x;
        int v = (i < N) ? counts[i] : 0;
        sm[threadIdx.x] = v;
        __syncthreads();
        for (int off = 1; off < 1024; off <<= 1) {
            int t = (threadIdx.x >= off) ? sm[threadIdx.x - off] : 0;
            __syncthreads();
            sm[threadIdx.x] += t;
            __syncthreads();
        }
        if (i < N) offsets[i] = carry + sm[threadIdx.x] - v;
        __syncthreads();
        if (threadIdx.x == 0) carry += sm[1023];
        __syncthreads();
    }
    if (threadIdx.x == 0) offsets[N] = Etot;
}

__global__ __launch_bounds__(256) void scatter_k(const int* __restrict__ ei, int E, int N,
                                                 int* __restrict__ cursor, int* __restrict__ eidx)
{
    int e = blockIdx.x * 256 + threadIdx.x;
    int Etot = E + N;
    if (e >= Etot) return;
    int s, d;
    if (e < E) { s = ei[e]; d = ei[E + e]; }
    else       { s = e - E; d = s; }
    int pos = atomicAdd(&cursor[d], 1);
    eidx[pos] = s;
}

__global__ void softmax6_k(const float* __restrict__ sw, float* __restrict__ w)
{
    if (threadIdx.x == 0 && blockIdx.x == 0) {
        float m = -1e30f;
        for (int l = 0; l < LL; ++l) m = fmaxf(m, sw[l]);
        float e[LL]; float s = 0.f;
        for (int l = 0; l < LL; ++l) { e[l] = __expf(sw[l] - m); s += e[l]; }
        for (int l = 0; l < LL; ++l) w[l] = e[l] / s;
    }
}

// ------- Edge aggregation: wave per node, 4 edge slots (16 lanes x 16 ch each), fp16 -----
__global__ __launch_bounds__(256) void edge_k(
    const __half* __restrict__ xlr, const __half* __restrict__ atth,
    const float* __restrict__ convb,
    const int* __restrict__ offsets, const int* __restrict__ eidx,
    float* __restrict__ h, float* __restrict__ hsum,
    __half* __restrict__ normed, __half* __restrict__ hsb,
    const float* __restrict__ wsm, const float* __restrict__ scales,
    int layer, int N)
{
    int wv = blockIdx.x * 4 + (threadIdx.x >> 6);
    if (wv >= N) return;
    int lane = threadIdx.x & 63;
    int slot = lane >> 4, sl = lane & 15;
    int c16 = sl * 16;

    __half2 atv[8], xrv[8];
    {
        uint4 a0 = *(const uint4*)(atth + c16);
        uint4 a1 = *(const uint4*)(atth + c16 + 8);
        atv[0]=u2h2(a0.x); atv[1]=u2h2(a0.y); atv[2]=u2h2(a0.z); atv[3]=u2h2(a0.w);
        atv[4]=u2h2(a1.x); atv[5]=u2h2(a1.y); atv[6]=u2h2(a1.z); atv[7]=u2h2(a1.w);
        uint4 x0 = *(const uint4*)(xlr + (size_t)wv * 512 + 256 + c16);
        uint4 x1 = *(const uint4*)(xlr + (size_t)wv * 512 + 256 + c16 + 8);
        xrv[0]=u2h2(x0.x); xrv[1]=u2h2(x0.y); xrv[2]=u2h2(x0.z); xrv[3]=u2h2(x0.w);
        xrv[4]=u2h2(x1.x); xrv[5]=u2h2(x1.y); xrv[6]=u2h2(x1.z); xrv[7]=u2h2(x1.w);
    }
    int e0 = offsets[wv], e1 = offsets[wv + 1];
    float den = 0.f;
    float a[16];
#pragma unroll
    for (int j = 0; j < 16; ++j) a[j] = 0.f;

    for (int e = e0 + slot; e < e1; e += 4) {
        int s = eidx[e];
        const __half* xp = xlr + (size_t)s * 512 + c16;
        uint4 w0 = *(const uint4*)xp;
        uint4 w1 = *(const uint4*)(xp + 8);
        __half2 x2[8];
        x2[0]=u2h2(w0.x); x2[1]=u2h2(w0.y); x2[2]=u2h2(w0.z); x2[3]=u2h2(w0.w);
        x2[4]=u2h2(w1.x); x2[5]=u2h2(w1.y); x2[6]=u2h2(w1.z); x2[7]=u2h2(w1.w);
        float pm = 0.f;
#pragma unroll
        for (int p = 0; p < 8; ++p) {
            __half2 t = lrelu2_02(__hadd2(x2[p], xrv[p]));   // leaky 0.2
            pm = dot2(atv[p], t, pm);
        }
        pm += __shfl_xor(pm, 1);               // head = 2 lanes
        float ex = __expf(pm);
        den += ex;
#pragma unroll
        for (int p = 0; p < 8; ++p) {
            a[2 * p]     = fmaf(__low2float(x2[p]),  ex, a[2 * p]);
            a[2 * p + 1] = fmaf(__high2float(x2[p]), ex, a[2 * p + 1]);
        }
    }
    den += __shfl_xor(den, 16);
    den += __shfl_xor(den, 32);
#pragma unroll
    for (int j = 0; j < 16; ++j) {
        a[j] += __shfl_xor(a[j], 16);
        a[j] += __shfl_xor(a[j], 32);
    }
    if (slot) return;   // epilogue on lanes 0..15

    float inv = 1.f / den;
    size_t base = (size_t)wv * 256 + c16;
    float cb[16], res[16], hn[16];
#pragma unroll
    for (int q4 = 0; q4 < 4; ++q4) {
        *(float4*)&cb[q4 * 4]  = *(const float4*)(convb + c16 + q4 * 4);
        *(float4*)&res[q4 * 4] = *(const float4*)(h + base + q4 * 4);
    }
    float sc = scales[layer], wl = wsm[layer];
#pragma unroll
    for (int j = 0; j < 16; ++j)
        hn[j] = fmaf(sc, leaky(fmaf(a[j], inv, cb[j]), 0.1f), res[j]);
#pragma unroll
    for (int q4 = 0; q4 < 4; ++q4)
        *(float4*)(h + base + q4 * 4) = *(float4*)&hn[q4 * 4];

    float hs[16];
    if (layer == 0) {
#pragma unroll
        for (int j = 0; j < 16; ++j) hs[j] = wl * hn[j];
    } else {
#pragma unroll
        for (int q4 = 0; q4 < 4; ++q4) *(float4*)&hs[q4 * 4] = *(const float4*)(hsum + base + q4 * 4);
#pragma unroll
        for (int j = 0; j < 16; ++j) hs[j] = fmaf(wl, hn[j], hs[j]);
    }
#pragma unroll
    for (int q4 = 0; q4 < 4; ++q4)
        *(float4*)(hsum + base + q4 * 4) = *(float4*)&hs[q4 * 4];

    if (hsb) {
        // last layer: write final weighted sum as fp16 (feeds exit MLP GEMM)
        uint4 o0, o1;
        o0.x = h22u(__floats2half2_rn(hs[0], hs[1]));
        o0.y = h22u(__floats2half2_rn(hs[2], hs[3]));
        o0.z = h22u(__floats2half2_rn(hs[4], hs[5]));
        o0.w = h22u(__floats2half2_rn(hs[6], hs[7]));
        o1.x = h22u(__floats2half2_rn(hs[8], hs[9]));
        o1.y = h22u(__floats2half2_rn(hs[10], hs[11]));
        o1.z = h22u(__floats2half2_rn(hs[12], hs[13]));
        o1.w = h22u(__floats2half2_rn(hs[14], hs[15]));
        *(uint4*)((unsigned short*)hsb + base) = o0;
        *(uint4*)((unsigned short*)hsb + base + 8) = o1;
    } else {
        // fused LN stats + normed fp16 for next layer's GEMM
        float s1 = 0.f;
#pragma unroll
        for (int j = 0; j < 16; ++j) s1 += hn[j];
#pragma unroll
        for (int off = 1; off < 16; off <<= 1) s1 += __shfl_xor(s1, off);
        float m = s1 * (1.f / 256.f);
        float q = 0.f;
#pragma unroll
        for (int j = 0; j < 16; ++j) { float d = hn[j] - m; q = fmaf(d, d, q); }
#pragma unroll
        for (int off = 1; off < 16; off <<= 1) q += __shfl_xor(q, off);
        float rs = rsqrtf(q * (1.f / 256.f) + EPSF);
        uint4 o0, o1;
        o0.x = h22u(__floats2half2_rn((hn[0] - m) * rs, (hn[1] - m) * rs));
        o0.y = h22u(__floats2half2_rn((hn[2] - m) * rs, (hn[3] - m) * rs));
        o0.z = h22u(__floats2half2_rn((hn[4] - m) * rs, (hn[5] - m) * rs));
        o0.w = h22u(__floats2half2_rn((hn[6] - m) * rs, (hn[7] - m) * rs));
        o1.x = h22u(__floats2half2_rn((hn[8] - m) * rs, (hn[9] - m) * rs));
        o1.y = h22u(__floats2half2_rn((hn[10] - m) * rs, (hn[11] - m) * rs));
        o1.z = h22u(__floats2half2_rn((hn[12] - m) * rs, (hn[13] - m) * rs));
        o1.w = h22u(__floats2half2_rn((hn[14] - m) * rs, (hn[15] - m) * rs));
        *(uint4*)((unsigned short*)normed + base) = o0;
        *(uint4*)((unsigned short*)normed + base + 8) = o1;
    }
}

// ---------------- final y2[N,128] @ h3_w[128,1] + h3_b ----------------
__global__ __launch_bounds__(256) void out_k(const float* __restrict__ y2,
                                             const float* __restrict__ w,
                                             const float* __restrict__ b,
                                             float* __restrict__ out, int N)
{
    int wv = blockIdx.x * 4 + (threadIdx.x >> 6);
    if (wv >= N) return;
    int lane = threadIdx.x & 63;
    float2 v = *(const float2*)(y2 + (size_t)wv * 128 + lane * 2);
    float2 ww = *(const float2*)(w + lane * 2);
    float pm = v.x * ww.x + v.y * ww.y;
#pragma unroll
    for (int off = 1; off < 64; off <<= 1) pm += __shfl_xor(pm, off);
    if (lane == 0) out[wv] = pm + b[0];
}

extern "C" void kernel_launch(void* const* d_in, const int* in_sizes, int n_in,
                              void* d_out, int out_size, void* d_ws, size_t ws_size,
                              hipStream_t stream)
{
    const int N = NN, E = EE, Etot = EE + NN;
    const float* x      = (const float*)d_in[0];
    const int*   ei     = (const int*)  d_in[1];
    const float* win_w  = (const float*)d_in[2];
    const float* win_b  = (const float*)d_in[3];
    const float* bn1_g  = (const float*)d_in[4];
    const float* bn1_b  = (const float*)d_in[5];
    const float* ln_g   = (const float*)d_in[6];
    const float* ln_b   = (const float*)d_in[7];
    const float* Wl     = (const float*)d_in[8];
    const float* bl     = (const float*)d_in[9];
    const float* Wr     = (const float*)d_in[10];
    const float* br     = (const float*)d_in[11];
    const float* att    = (const float*)d_in[12];
    const float* conv_b = (const float*)d_in[13];
    const float* scales = (const float*)d_in[14];
    const float* sw     = (const float*)d_in[15];
    const float* h1_w   = (const float*)d_in[16];
    const float* h1_b   = (const float*)d_in[17];
    const float* bn2_g  = (const float*)d_in[18];
    const float* bn2_b  = (const float*)d_in[19];
    const float* h2_w   = (const float*)d_in[20];
    const float* h2_b   = (const float*)d_in[21];
    const float* h3_w   = (const float*)d_in[22];
    const float* h3_b   = (const float*)d_in[23];

    char* p = (char*)d_ws;
    auto take = [&](size_t b) -> char* {
        char* q = p; p += (b + 255) & ~(size_t)255; return q;
    };
    float* h        = (float*)take((size_t)N * 256 * 4);
    float* hsum     = (float*)take((size_t)N * 256 * 4);
    __half* norm    = (__half*)take((size_t)N * 256 * 2);   // also final-sum fp16 after layer 5
    __half* xlr     = (__half*)take((size_t)N * 512 * 2);
    __half* xh      = (__half*)take((size_t)N * 128 * 2);
    float* wsm      = (float*)take(256);
    int*   offsets  = (int*)take((size_t)(N + 1) * 4);
    int*   cursor   = (int*)take((size_t)N * 4);
    int*   eidx     = (int*)take((size_t)Etot * 4);
    __half* winT    = (__half*)take((size_t)256 * 128 * 2);
    __half* WlrT    = (__half*)take((size_t)LL * 512 * 256 * 2);
    __half* h1T     = (__half*)take((size_t)256 * 256 * 2);
    __half* h2T     = (__half*)take((size_t)128 * 256 * 2);
    __half* att_h   = (__half*)take((size_t)LL * 256 * 2);
    float* biasLR   = (float*)take((size_t)LL * 512 * 4);
    __half* y1b = xlr;                                      // xlr dead after layer-5 edge_k
    float*  y2  = (float*)(xlr + (size_t)N * 256);          // second half of xlr region

    const int EB = (Etot + 255) / 256;
    const int NB = (N + 3) / 4;

    // CSR build
    hipMemsetAsync(cursor, 0, (size_t)N * 4, stream);
    hist_k<<<EB, 256, 0, stream>>>(ei, E, N, cursor);
    scan_k<<<1, 1024, 0, stream>>>(cursor, offsets, N, Etot);
    hipMemcpyAsync(cursor, offsets, (size_t)N * 4, hipMemcpyDeviceToDevice, stream);
    scatter_k<<<EB, 256, 0, stream>>>(ei, E, N, cursor, eidx);
    softmax6_k<<<1, 64, 0, stream>>>(sw, wsm);

    // weight prep (fp16): gamma folded into Wl/Wr rows; beta folded into biasLR
    cvt_t_k<<<dim3(2, 4), 256, 0, stream>>>(win_w, winT, nullptr, 128, 256);
    for (int l = 0; l < LL; ++l) {
        cvt_t_k<<<dim3(4, 4), 256, 0, stream>>>(Wl + (size_t)l * 65536,
            WlrT + (size_t)l * 131072, ln_g + l * 256, 256, 256);
        cvt_t_k<<<dim3(4, 4), 256, 0, stream>>>(Wr + (size_t)l * 65536,
            WlrT + (size_t)l * 131072 + 65536, ln_g + l * 256, 256, 256);
    }
    cvt_t_k<<<dim3(4, 4), 256, 0, stream>>>(h1_w, h1T, nullptr, 256, 256);
    cvt_t_k<<<dim3(4, 2), 256, 0, stream>>>(h2_w, h2T, nullptr, 256, 128);
    biasfold_k<<<dim3(LL, 2), 256, 0, stream>>>(bl, br, ln_b, Wl, Wr, biasLR);
    cvt_h_k<<<LL, 256, 0, stream>>>(att, att_h, LL * 256);
    cvt_h_k<<<(N * 128 + 255) / 256, 256, 0, stream>>>(x, xh, N * 128);

    dim3 g2d((N + 127) / 128, 2);   // 391 x 2
    dim3 g4d((N + 127) / 128, 4);   // 391 x 4

    // entry: h = leaky(bn1(x @ win_w + win_b), 0.1); norm for layer 0
    gemm_h_k<1, false><<<g2d, 256, 0, stream>>>(xh, winT, win_b, bn1_g, bn1_b, h, N, 128, 256);
    ln_norm_k<<<NB, 256, 0, stream>>>(h, norm, N);

    for (int l = 0; l < LL; ++l) {
        gemm_h_k<0, true><<<g4d, 256, 0, stream>>>(norm, WlrT + (size_t)l * 131072,
                                                   biasLR + l * 512, nullptr, nullptr,
                                                   xlr, N, 256, 512);
        edge_k<<<NB, 256, 0, stream>>>(xlr, att_h + l * 256, conv_b + l * 256,
                                       offsets, eidx, h, hsum, norm,
                                       (l == LL - 1) ? norm : nullptr,
                                       wsm, scales, l, N);
    }

    // exit MLP: y1 = leaky(bn2(sum @ h1_w + h1_b)); y2 = leaky(y1 @ h2_w + h2_b); out
    gemm_h_k<1, true><<<g2d, 256, 0, stream>>>(norm, h1T, h1_b, bn2_g, bn2_b, y1b, N, 256, 256);
    gemm_h_k<2, false><<<dim3((N + 127) / 128, 1), 256, 0, stream>>>(
        y1b, h2T, h2_b, nullptr, nullptr, y2, N, 256, 128);
    out_k<<<NB, 256, 0, stream>>>(y2, h3_w, h3_b, (float*)d_out, N);
}

// Round 6
// 1160.473 us; speedup vs baseline: 2.2131x; 1.0365x over previous
//
#include <hip/hip_runtime.h>
#include <hip/hip_fp16.h>

#define NN 50000
#define EE 800000
#define LL 6
constexpr float EPSF = 1e-5f;

typedef _Float16 f16x8 __attribute__((ext_vector_type(8)));
typedef _Float16 f16x2 __attribute__((ext_vector_type(2)));
typedef float f32x4 __attribute__((ext_vector_type(4)));
typedef unsigned short u16x8 __attribute__((ext_vector_type(8)));

__device__ __forceinline__ float leaky(float v, float s) { return v > 0.f ? v : s * v; }

__device__ __forceinline__ f16x2 asf2(unsigned int u) {
    union { unsigned int u; f16x2 f; } x; x.u = u; return x.f;
}
__device__ __forceinline__ unsigned int asu2(f16x2 f) {
    union { f16x2 f; unsigned int u; } x; x.f = f; return x.u;
}
__device__ __forceinline__ f16x2 lrelu2_02(f16x2 v) {
    return __builtin_elementwise_max(v, v * (_Float16)0.2f);
}
__device__ __forceinline__ f16x2 pk2(float a, float b) {
    f16x2 r; r[0] = (_Float16)a; r[1] = (_Float16)b; return r;
}

union Row16 { uint4 u4[4]; unsigned int w[16]; };

// async global->LDS, 16B per lane
#define GLD16(gp, sp) __builtin_amdgcn_global_load_lds( \
    (const __attribute__((address_space(1))) unsigned int*)(uintptr_t)(gp), \
    (__attribute__((address_space(3))) unsigned int*)(uintptr_t)(sp), 16, 0, 0)

// ------------- fused prep: all transposes + biasfold + att cvt + softmax -------------
__global__ __launch_bounds__(256) void prep_k(
    const float* __restrict__ win_w, const float* __restrict__ Wl,
    const float* __restrict__ Wr, const float* __restrict__ h1_w,
    const float* __restrict__ h2_w, const float* __restrict__ ln_g,
    const float* __restrict__ ln_b, const float* __restrict__ bl,
    const float* __restrict__ br, const float* __restrict__ att,
    const float* __restrict__ sw,
    __half* __restrict__ winT, __half* __restrict__ WlrT,
    __half* __restrict__ h1T, __half* __restrict__ h2T,
    __half* __restrict__ att_h, float* __restrict__ biasLR, float* __restrict__ wsm)
{
    __shared__ float t[64][65];
    const int bid = blockIdx.x, tid = threadIdx.x;
    if (bid < 224) {
        const float* in; __half* out; const float* gamma = nullptr;
        int K, N, kb, nb;
        if (bid < 8)        { in = win_w; out = winT; K = 128; N = 256; kb = bid >> 2; nb = bid & 3; }
        else if (bid < 104) { int i = bid - 8; int l = i >> 4, r = i & 15;
            in = Wl + (size_t)l * 65536; out = WlrT + (size_t)l * 131072;
            gamma = ln_g + l * 256; K = 256; N = 256; kb = r >> 2; nb = r & 3; }
        else if (bid < 200) { int i = bid - 104; int l = i >> 4, r = i & 15;
            in = Wr + (size_t)l * 65536; out = WlrT + (size_t)l * 131072 + 65536;
            gamma = ln_g + l * 256; K = 256; N = 256; kb = r >> 2; nb = r & 3; }
        else if (bid < 216) { int i = bid - 200; in = h1_w; out = h1T; K = 256; N = 256; kb = i >> 2; nb = i & 3; }
        else                { int i = bid - 216; in = h2_w; out = h2T; K = 256; N = 128; kb = i >> 1; nb = i & 1; }
        const int k0 = kb * 64, n0 = nb * 64;
        {
            int kl = tid >> 2, np = (tid & 3) * 16;
            const float* ip = in + (size_t)(k0 + kl) * N + n0 + np;
            float4 a = *(const float4*)(ip + 0);
            float4 b = *(const float4*)(ip + 4);
            float4 c = *(const float4*)(ip + 8);
            float4 d = *(const float4*)(ip + 12);
            t[kl][np + 0] = a.x; t[kl][np + 1] = a.y; t[kl][np + 2] = a.z; t[kl][np + 3] = a.w;
            t[kl][np + 4] = b.x; t[kl][np + 5] = b.y; t[kl][np + 6] = b.z; t[kl][np + 7] = b.w;
            t[kl][np + 8] = c.x; t[kl][np + 9] = c.y; t[kl][np +10] = c.z; t[kl][np +11] = c.w;
            t[kl][np +12] = d.x; t[kl][np +13] = d.y; t[kl][np +14] = d.z; t[kl][np +15] = d.w;
        }
        __syncthreads();
        {
            int nl = tid >> 2, kp = (tid & 3) * 16;
            u16x8 o0, o1;
#pragma unroll
            for (int i = 0; i < 8; ++i) {
                float g0 = gamma ? gamma[k0 + kp + i] : 1.f;
                float g1 = gamma ? gamma[k0 + kp + 8 + i] : 1.f;
                o0[i] = __half_as_ushort(__float2half(t[kp + i][nl] * g0));
                o1[i] = __half_as_ushort(__float2half(t[kp + 8 + i][nl] * g1));
            }
            unsigned short* op = (unsigned short*)out + (size_t)(n0 + nl) * K + k0 + kp;
            *(u16x8*)(op + 0) = o0;
            *(u16x8*)(op + 8) = o1;
        }
    } else if (bid < 236) {
        int i = bid - 224, l = i >> 1, side = i & 1, n = tid;
        const float* W = side ? Wr : Wl;
        const float* b = side ? br : bl;
        const float* lb = ln_b + l * 256;
        const float* Wp = W + (size_t)l * 65536;
        float acc = b[l * 256 + n];
        for (int k = 0; k < 256; ++k) acc = fmaf(lb[k], Wp[(size_t)k * 256 + n], acc);
        biasLR[l * 512 + side * 256 + n] = acc;
    } else if (bid < 242) {
        int l = bid - 236;
        att_h[l * 256 + tid] = __float2half(att[l * 256 + tid]);
    } else if (tid == 0) {
        float m = -1e30f;
        for (int l = 0; l < LL; ++l) m = fmaxf(m, sw[l]);
        float e[LL]; float s = 0.f;
        for (int l = 0; l < LL; ++l) { e[l] = __expf(sw[l] - m); s += e[l]; }
        float w[LL];
        for (int l = 0; l < LL; ++l) { w[l] = e[l] / s; wsm[l] = w[l]; }
        for (int l = 0; l < LL; ++l) {
            float S = 0.f;
            for (int k = l; k < LL; ++k) S += w[k];
            wsm[8 + l] = S;   // suffix sums
        }
    }
}

// ------- generic fp32 -> fp16 -------
__global__ __launch_bounds__(256) void cvt_h_k(const float* __restrict__ in,
                                               __half* __restrict__ out, int n)
{
    int i = blockIdx.x * 256 + threadIdx.x;
    if (i < n) out[i] = __float2half(in[i]);
}

// ------- fp16 MFMA GEMM, 128x128 tile, BK=64, global_load_lds staging, XOR swizzle ----
template<int ACT, bool OHALF>
__global__ __launch_bounds__(256) void gemm_h_k(
    const __half* __restrict__ A, const __half* __restrict__ Bt,
    const float* __restrict__ bias, const float* __restrict__ g2,
    const float* __restrict__ b2, void* __restrict__ Cv,
    int M, int K, int N)
{
    __shared__ _Float16 As[128 * 64];
    __shared__ _Float16 Bs[128 * 64];
    const int tid = threadIdx.x, lane = tid & 63, wave = tid >> 6;
    const int bm = blockIdx.x * 128, bn = blockIdx.y * 128;
    const int wm = (wave & 1) * 64, wn = (wave >> 1) * 64;
    const int mrow = lane & 15;
    const int sg = lane >> 3;
    const int sc = (lane & 7) ^ sg;

    f32x4 acc[4][4];
#pragma unroll
    for (int i = 0; i < 4; ++i)
#pragma unroll
        for (int j = 0; j < 4; ++j) acc[i][j] = (f32x4){0.f, 0.f, 0.f, 0.f};

    for (int k0 = 0; k0 < K; k0 += 64) {
#pragma unroll
        for (int t = 0; t < 4; ++t) {
            int R = 32 * wave + 8 * t;
            int ar = bm + R + sg; if (ar >= M) ar = M - 1;
            GLD16(A + (size_t)ar * K + k0 + sc * 8, &As[R * 64]);
        }
#pragma unroll
        for (int t = 0; t < 4; ++t) {
            int R = 32 * wave + 8 * t;
            GLD16(Bt + (size_t)(bn + R + sg) * K + k0 + sc * 8, &Bs[R * 64]);
        }
        __syncthreads();
#pragma unroll
        for (int s2 = 0; s2 < 2; ++s2) {
            const int c = s2 * 4 + (lane >> 4);
            f16x8 af[4], bf[4];
#pragma unroll
            for (int i = 0; i < 4; ++i) {
                int r = wm + 16 * i + mrow;
                af[i] = *(const f16x8*)&As[r * 64 + ((c ^ (r & 7)) * 8)];
            }
#pragma unroll
            for (int j = 0; j < 4; ++j) {
                int r = wn + 16 * j + mrow;
                bf[j] = *(const f16x8*)&Bs[r * 64 + ((c ^ (r & 7)) * 8)];
            }
#pragma unroll
            for (int i = 0; i < 4; ++i)
#pragma unroll
                for (int j = 0; j < 4; ++j)
                    acc[i][j] = __builtin_amdgcn_mfma_f32_16x16x32_f16(af[i], bf[j], acc[i][j], 0, 0, 0);
        }
        __syncthreads();
    }

    const float inv_s = 0.9999950000374997f; // 1/sqrt(1+1e-5)
    const int rq = (lane >> 4) * 4;
    float bsj[4], gj[4], bbj[4];
#pragma unroll
    for (int j = 0; j < 4; ++j) {
        int cc = bn + wn + 16 * j + mrow;
        bsj[j] = bias[cc];
        if constexpr (ACT == 1) { gj[j] = g2[cc]; bbj[j] = b2[cc]; }
    }
#pragma unroll
    for (int i = 0; i < 4; ++i)
#pragma unroll
        for (int r = 0; r < 4; ++r) {
            int grow = bm + wm + 16 * i + rq + r;
            if (grow >= M) continue;
#pragma unroll
            for (int j = 0; j < 4; ++j) {
                int cc = bn + wn + 16 * j + mrow;
                float v = acc[i][j][r] + bsj[j];
                if constexpr (ACT == 1) v = leaky(v * inv_s * gj[j] + bbj[j], 0.1f);
                else if constexpr (ACT == 2) v = leaky(v, 0.1f);
                if constexpr (OHALF) ((__half*)Cv)[(size_t)grow * N + cc] = __float2half(v);
                else                 ((float*)Cv)[(size_t)grow * N + cc] = v;
            }
        }
}

// ------- entry LN: norm = (h16 - mu)*rsig -> fp16; hacc init = h16 -------
__global__ __launch_bounds__(256) void ln_norm_k(const __half* __restrict__ h16,
                                                 __half* __restrict__ hacc,
                                                 __half* __restrict__ normed, int N)
{
    int wv = blockIdx.x * 4 + (threadIdx.x >> 6);
    if (wv >= N) return;
    int lane = threadIdx.x & 63;
    size_t off = (size_t)wv * 256 + lane * 4;
    uint2 u = *(const uint2*)((const unsigned short*)h16 + off);
    f16x2 p0 = asf2(u.x), p1 = asf2(u.y);
    float v0 = (float)p0[0], v1 = (float)p0[1], v2 = (float)p1[0], v3 = (float)p1[1];
    float s = v0 + v1 + v2 + v3;
#pragma unroll
    for (int o = 1; o < 64; o <<= 1) s += __shfl_xor(s, o);
    float m = s * (1.f / 256.f);
    float d0 = v0 - m, d1 = v1 - m, d2 = v2 - m, d3 = v3 - m;
    float q = d0 * d0 + d1 * d1 + d2 * d2 + d3 * d3;
#pragma unroll
    for (int o = 1; o < 64; o <<= 1) q += __shfl_xor(q, o);
    float rs = rsqrtf(q * (1.f / 256.f) + EPSF);
    *(uint2*)((unsigned short*)hacc + off) = u;
    uint2 o2;
    o2.x = asu2(pk2(d0 * rs, d1 * rs));
    o2.y = asu2(pk2(d2 * rs, d3 * rs));
    *(uint2*)((unsigned short*)normed + off) = o2;
}

// ---------------- CSR build ----------------
__global__ __launch_bounds__(256) void hist_k(const int* __restrict__ ei, int E, int N,
                                              int* __restrict__ counts)
{
    int e = blockIdx.x * 256 + threadIdx.x;
    int Etot = E + N;
    if (e >= Etot) return;
    int d = (e < E) ? ei[E + e] : (e - E);
    atomicAdd(&counts[d], 1);
}

__global__ __launch_bounds__(1024) void scan_k(const int* __restrict__ counts,
                                               int* __restrict__ offsets, int N, int Etot)
{
    __shared__ int sm[1024];
    __shared__ int carry;
    if (threadIdx.x == 0) carry = 0;
    __syncthreads();
    for (int base = 0; base < N; base += 1024) {
        int i = base + threadIdx.x;
        int v = (i < N) ? counts[i] : 0;
        sm[threadIdx.x] = v;
        __syncthreads();
        for (int off = 1; off < 1024; off <<= 1) {
            int t = (threadIdx.x >= off) ? sm[threadIdx.x - off] : 0;
            __syncthreads();
            sm[threadIdx.x] += t;
            __syncthreads();
        }
        if (i < N) offsets[i] = carry + sm[threadIdx.x] - v;
        __syncthreads();
        if (threadIdx.x == 0) carry += sm[1023];
        __syncthreads();
    }
    if (threadIdx.x == 0) offsets[N] = Etot;
}

__global__ __launch_bounds__(256) void scatter_k(const int* __restrict__ ei, int E, int N,
                                                 int* __restrict__ cursor, int* __restrict__ eidx)
{
    int e = blockIdx.x * 256 + threadIdx.x;
    int Etot = E + N;
    if (e >= Etot) return;
    int s, d;
    if (e < E) { s = ei[e]; d = ei[E + e]; }
    else       { s = e - E; d = s; }
    int pos = atomicAdd(&cursor[d], 1);
    eidx[pos] = s;
}

// ------- Edge aggregation: wave/node, 8 slots x 8 lanes x 32 ch (lane = one head) -----
// No in-loop shfls (head logit completes in-lane); depth-1 prefetch; pk_fma fp16 accum.
__global__ __launch_bounds__(256) void edge_k(
    const __half* __restrict__ xlr, const __half* __restrict__ atth,
    const float* __restrict__ convb,
    const int* __restrict__ offsets, const int* __restrict__ eidx,
    __half* __restrict__ h16, __half* __restrict__ hacc,
    __half* __restrict__ normed,
    const float* __restrict__ wsm, const float* __restrict__ scales,
    int layer, int N)
{
    int wv = blockIdx.x * 4 + (threadIdx.x >> 6);
    if (wv >= N) return;
    const int lane = threadIdx.x & 63;
    const int slot = lane >> 3, q = lane & 7;

    f16x2 atv[16], xrv[16];
    {
        Row16 A_, X_;
        const unsigned short* ap = (const unsigned short*)atth + q * 32;
        const unsigned short* xp = (const unsigned short*)xlr + (size_t)wv * 512 + 256 + q * 32;
#pragma unroll
        for (int i = 0; i < 4; ++i) {
            A_.u4[i] = *(const uint4*)(ap + 8 * i);
            X_.u4[i] = *(const uint4*)(xp + 8 * i);
        }
#pragma unroll
        for (int p = 0; p < 16; ++p) { atv[p] = asf2(A_.w[p]); xrv[p] = asf2(X_.w[p]); }
    }

    const int e0 = offsets[wv], e1 = offsets[wv + 1], e1m = e1 - 1;
    f16x2 a2[16];
#pragma unroll
    for (int p = 0; p < 16; ++p) a2[p] = pk2(0.f, 0.f);
    float den = 0.f;

    // prologue: load edge e0+slot
    int e = e0 + slot;
    bool v = e < e1;
    int s = eidx[v ? e : e1m];
    Row16 W;
    {
        const unsigned short* xp = (const unsigned short*)xlr + (size_t)s * 512 + q * 32;
#pragma unroll
        for (int i = 0; i < 4; ++i) W.u4[i] = *(const uint4*)(xp + 8 * i);
    }
    int base = e0;
    while (true) {
        int nbase = base + 8;
        bool more = nbase < e1;           // wave-uniform
        Row16 NW; bool nv = false;
        if (more) {
            int ne = nbase + slot;
            nv = ne < e1;
            int ns = eidx[nv ? ne : e1m];
            const unsigned short* np = (const unsigned short*)xlr + (size_t)ns * 512 + q * 32;
#pragma unroll
            for (int i = 0; i < 4; ++i) NW.u4[i] = *(const uint4*)(np + 8 * i);
        }
        float pm = 0.f;
        f16x2 xv[16];
#pragma unroll
        for (int p = 0; p < 16; ++p) {
            xv[p] = asf2(W.w[p]);
            f16x2 t = lrelu2_02(xv[p] + xrv[p]);
            pm = __builtin_amdgcn_fdot2(t, atv[p], pm, false);
        }
        float exf = v ? __expf(pm) : 0.f;
        den += exf;
        _Float16 eh = (_Float16)exf;
        f16x2 e2; e2[0] = eh; e2[1] = eh;
#pragma unroll
        for (int p = 0; p < 16; ++p) a2[p] += xv[p] * e2;
        if (!more) break;
        W = NW; v = nv; base = nbase;
    }

    // combine across the 8 slots (lane bits 3,4,5)
    den += __shfl_xor(den, 8); den += __shfl_xor(den, 16); den += __shfl_xor(den, 32);
#pragma unroll
    for (int p = 0; p < 16; ++p) {
        a2[p] += asf2((unsigned int)__shfl_xor((int)asu2(a2[p]), 8));
        a2[p] += asf2((unsigned int)__shfl_xor((int)asu2(a2[p]), 16));
        a2[p] += asf2((unsigned int)__shfl_xor((int)asu2(a2[p]), 32));
    }
    if (lane >= 8) return;   // epilogue on lanes 0..7; q = lane, 32 ch each

    const float inv = 1.f / den;
    const float sc = scales[layer], Sl = wsm[8 + layer];
    const size_t rb = (size_t)wv * 256 + q * 32;
    float cb[32];
#pragma unroll
    for (int i = 0; i < 8; ++i) *(float4*)&cb[4 * i] = *(const float4*)(convb + q * 32 + 4 * i);

    Row16 H_;
    const unsigned short* hp = (const unsigned short*)h16 + rb;
#pragma unroll
    for (int i = 0; i < 4; ++i) H_.u4[i] = *(const uint4*)(hp + 8 * i);

    float d[32], hn[32];
#pragma unroll
    for (int p = 0; p < 16; ++p) {
        float o0 = fmaf((float)a2[p][0], inv, cb[2 * p]);
        float o1 = fmaf((float)a2[p][1], inv, cb[2 * p + 1]);
        d[2 * p]     = sc * leaky(o0, 0.1f);
        d[2 * p + 1] = sc * leaky(o1, 0.1f);
        f16x2 r = asf2(H_.w[p]);
        hn[2 * p]     = (float)r[0] + d[2 * p];
        hn[2 * p + 1] = (float)r[1] + d[2 * p + 1];
    }

    // hacc += S_l * d   (hsum = h_entry + sum_l S_l d_l, since softmax weights sum to 1)
    {
        Row16 HA, HO;
        const unsigned short* ha = (const unsigned short*)hacc + rb;
#pragma unroll
        for (int i = 0; i < 4; ++i) HA.u4[i] = *(const uint4*)(ha + 8 * i);
#pragma unroll
        for (int p = 0; p < 16; ++p) {
            f16x2 hv = asf2(HA.w[p]);
            HO.w[p] = asu2(pk2(fmaf(Sl, d[2 * p],     (float)hv[0]),
                               fmaf(Sl, d[2 * p + 1], (float)hv[1])));
        }
#pragma unroll
        for (int i = 0; i < 4; ++i) *(uint4*)((unsigned short*)hacc + rb + 8 * i) = HO.u4[i];
    }

    if (layer != LL - 1) {
        Row16 HN;
#pragma unroll
        for (int p = 0; p < 16; ++p) HN.w[p] = asu2(pk2(hn[2 * p], hn[2 * p + 1]));
#pragma unroll
        for (int i = 0; i < 4; ++i) *(uint4*)((unsigned short*)h16 + rb + 8 * i) = HN.u4[i];
        // LN stats across the 8 lanes
        float s1 = 0.f;
#pragma unroll
        for (int j = 0; j < 32; ++j) s1 += hn[j];
        s1 += __shfl_xor(s1, 1); s1 += __shfl_xor(s1, 2); s1 += __shfl_xor(s1, 4);
        float m = s1 * (1.f / 256.f);
        float qv = 0.f;
#pragma unroll
        for (int j = 0; j < 32; ++j) { float dd = hn[j] - m; qv = fmaf(dd, dd, qv); }
        qv += __shfl_xor(qv, 1); qv += __shfl_xor(qv, 2); qv += __shfl_xor(qv, 4);
        float rs = rsqrtf(qv * (1.f / 256.f) + EPSF);
        Row16 NO;
#pragma unroll
        for (int p = 0; p < 16; ++p)
            NO.w[p] = asu2(pk2((hn[2 * p] - m) * rs, (hn[2 * p + 1] - m) * rs));
#pragma unroll
        for (int i = 0; i < 4; ++i) *(uint4*)((unsigned short*)normed + rb + 8 * i) = NO.u4[i];
    }
}

// ---------------- final y2[N,128] @ h3_w[128,1] + h3_b ----------------
__global__ __launch_bounds__(256) void out_k(const float* __restrict__ y2,
                                             const float* __restrict__ w,
                                             const float* __restrict__ b,
                                             float* __restrict__ out, int N)
{
    int wv = blockIdx.x * 4 + (threadIdx.x >> 6);
    if (wv >= N) return;
    int lane = threadIdx.x & 63;
    float2 v = *(const float2*)(y2 + (size_t)wv * 128 + lane * 2);
    float2 ww = *(const float2*)(w + lane * 2);
    float pm = v.x * ww.x + v.y * ww.y;
#pragma unroll
    for (int off = 1; off < 64; off <<= 1) pm += __shfl_xor(pm, off);
    if (lane == 0) out[wv] = pm + b[0];
}

extern "C" void kernel_launch(void* const* d_in, const int* in_sizes, int n_in,
                              void* d_out, int out_size, void* d_ws, size_t ws_size,
                              hipStream_t stream)
{
    const int N = NN, E = EE, Etot = EE + NN;
    const float* x      = (const float*)d_in[0];
    const int*   ei     = (const int*)  d_in[1];
    const float* win_w  = (const float*)d_in[2];
    const float* win_b  = (const float*)d_in[3];
    const float* bn1_g  = (const float*)d_in[4];
    const float* bn1_b  = (const float*)d_in[5];
    const float* ln_g   = (const float*)d_in[6];
    const float* ln_b   = (const float*)d_in[7];
    const float* Wl     = (const float*)d_in[8];
    const float* bl     = (const float*)d_in[9];
    const float* Wr     = (const float*)d_in[10];
    const float* br     = (const float*)d_in[11];
    const float* att    = (const float*)d_in[12];
    const float* conv_b = (const float*)d_in[13];
    const float* scales = (const float*)d_in[14];
    const float* sw     = (const float*)d_in[15];
    const float* h1_w   = (const float*)d_in[16];
    const float* h1_b   = (const float*)d_in[17];
    const float* bn2_g  = (const float*)d_in[18];
    const float* bn2_b  = (const float*)d_in[19];
    const float* h2_w   = (const float*)d_in[20];
    const float* h2_b   = (const float*)d_in[21];
    const float* h3_w   = (const float*)d_in[22];
    const float* h3_b   = (const float*)d_in[23];

    char* p = (char*)d_ws;
    auto take = [&](size_t b) -> char* {
        char* q = p; p += (b + 255) & ~(size_t)255; return q;
    };
    __half* h16     = (__half*)take((size_t)N * 256 * 2);
    __half* hacc    = (__half*)take((size_t)N * 256 * 2);
    __half* norm    = (__half*)take((size_t)N * 256 * 2);
    __half* xlr     = (__half*)take((size_t)N * 512 * 2);
    __half* xh      = (__half*)take((size_t)N * 128 * 2);
    float* wsm      = (float*)take(256);
    int*   offsets  = (int*)take((size_t)(N + 1) * 4);
    int*   cursor   = (int*)take((size_t)N * 4);
    int*   eidx     = (int*)take((size_t)Etot * 4);
    __half* winT    = (__half*)take((size_t)256 * 128 * 2);
    __half* WlrT    = (__half*)take((size_t)LL * 512 * 256 * 2);
    __half* h1T     = (__half*)take((size_t)256 * 256 * 2);
    __half* h2T     = (__half*)take((size_t)128 * 256 * 2);
    __half* att_h   = (__half*)take((size_t)LL * 256 * 2);
    float* biasLR   = (float*)take((size_t)LL * 512 * 4);
    __half* y1b = xlr;                                      // xlr dead after layer-5 edge_k
    float*  y2  = (float*)(xlr + (size_t)N * 256);          // second half of xlr region

    const int EB = (Etot + 255) / 256;
    const int NB = (N + 3) / 4;

    // CSR build
    hipMemsetAsync(cursor, 0, (size_t)N * 4, stream);
    hist_k<<<EB, 256, 0, stream>>>(ei, E, N, cursor);
    scan_k<<<1, 1024, 0, stream>>>(cursor, offsets, N, Etot);
    hipMemcpyAsync(cursor, offsets, (size_t)N * 4, hipMemcpyDeviceToDevice, stream);
    scatter_k<<<EB, 256, 0, stream>>>(ei, E, N, cursor, eidx);

    // fused prep: transposes(+gamma fold), biasfold(+beta fold), att cvt, softmax+suffix
    prep_k<<<243, 256, 0, stream>>>(win_w, Wl, Wr, h1_w, h2_w, ln_g, ln_b, bl, br, att, sw,
                                    winT, WlrT, h1T, h2T, att_h, biasLR, wsm);
    cvt_h_k<<<(N * 128 + 255) / 256, 256, 0, stream>>>(x, xh, N * 128);

    dim3 g2d((N + 127) / 128, 2);   // 391 x 2
    dim3 g4d((N + 127) / 128, 4);   // 391 x 4

    // entry: h16 = leaky(bn1(x @ win_w + win_b), 0.1) fp16; norm + hacc init
    gemm_h_k<1, true><<<g2d, 256, 0, stream>>>(xh, winT, win_b, bn1_g, bn1_b, h16, N, 128, 256);
    ln_norm_k<<<NB, 256, 0, stream>>>(h16, hacc, norm, N);

    for (int l = 0; l < LL; ++l) {
        gemm_h_k<0, true><<<g4d, 256, 0, stream>>>(norm, WlrT + (size_t)l * 131072,
                                                   biasLR + l * 512, nullptr, nullptr,
                                                   xlr, N, 256, 512);
        edge_k<<<NB, 256, 0, stream>>>(xlr, att_h + l * 256, conv_b + l * 256,
                                       offsets, eidx, h16, hacc, norm,
                                       wsm, scales, l, N);
    }

    // exit MLP on hacc (= softmax-weighted layer sum, fp16)
    gemm_h_k<1, true><<<g2d, 256, 0, stream>>>(hacc, h1T, h1_b, bn2_g, bn2_b, y1b, N, 256, 256);
    gemm_h_k<2, false><<<dim3((N + 127) / 128, 1), 256, 0, stream>>>(
        y1b, h2T, h2_b, nullptr, nullptr, y2, N, 256, 128);
    out_k<<<NB, 256, 0, stream>>>(y2, h3_w, h3_b, (float*)d_out, N);
}

// Round 7
// 989.740 us; speedup vs baseline: 2.5948x; 1.1725x over previous
//
#include <hip/hip_runtime.h>
#include <hip/hip_fp16.h>

#define NN 50000
#define EE 800000
#define LL 6
constexpr float EPSF = 1e-5f;

typedef _Float16 f16x8 __attribute__((ext_vector_type(8)));
typedef _Float16 f16x2 __attribute__((ext_vector_type(2)));
typedef float f32x4 __attribute__((ext_vector_type(4)));
typedef unsigned short u16x8 __attribute__((ext_vector_type(8)));

__device__ __forceinline__ float leaky(float v, float s) { return v > 0.f ? v : s * v; }

__device__ __forceinline__ f16x2 asf2(unsigned int u) {
    union { unsigned int u; f16x2 f; } x; x.u = u; return x.f;
}
__device__ __forceinline__ unsigned int asu2(f16x2 f) {
    union { f16x2 f; unsigned int u; } x; x.f = f; return x.u;
}
__device__ __forceinline__ f16x2 lrelu2_02(f16x2 v) {
    return __builtin_elementwise_max(v, v * (_Float16)0.2f);
}
__device__ __forceinline__ f16x2 pk2(float a, float b) {
    f16x2 r; r[0] = (_Float16)a; r[1] = (_Float16)b; return r;
}
// fp32 -> one fp8 e4m3 byte
__device__ __forceinline__ unsigned char f2fp8(float v) {
    return (unsigned char)(__builtin_amdgcn_cvt_pk_fp8_f32(v, v, 0, false) & 0xff);
}

// async global->LDS, 16B per lane
#define GLD16(gp, sp) __builtin_amdgcn_global_load_lds( \
    (const __attribute__((address_space(1))) unsigned int*)(uintptr_t)(gp), \
    (__attribute__((address_space(3))) unsigned int*)(uintptr_t)(sp), 16, 0, 0)

// ------------- fused prep: all transposes + biasfold + att cvt + softmax -------------
__global__ __launch_bounds__(256) void prep_k(
    const float* __restrict__ win_w, const float* __restrict__ Wl,
    const float* __restrict__ Wr, const float* __restrict__ h1_w,
    const float* __restrict__ h2_w, const float* __restrict__ ln_g,
    const float* __restrict__ ln_b, const float* __restrict__ bl,
    const float* __restrict__ br, const float* __restrict__ att,
    const float* __restrict__ sw,
    __half* __restrict__ winT, __half* __restrict__ WlrT,
    __half* __restrict__ h1T, __half* __restrict__ h2T,
    __half* __restrict__ att_h, float* __restrict__ biasLR, float* __restrict__ wsm)
{
    __shared__ float t[64][65];
    const int bid = blockIdx.x, tid = threadIdx.x;
    if (bid < 224) {
        const float* in; __half* out; const float* gamma = nullptr;
        int K, N, kb, nb;
        if (bid < 8)        { in = win_w; out = winT; K = 128; N = 256; kb = bid >> 2; nb = bid & 3; }
        else if (bid < 104) { int i = bid - 8; int l = i >> 4, r = i & 15;
            in = Wl + (size_t)l * 65536; out = WlrT + (size_t)l * 131072;
            gamma = ln_g + l * 256; K = 256; N = 256; kb = r >> 2; nb = r & 3; }
        else if (bid < 200) { int i = bid - 104; int l = i >> 4, r = i & 15;
            in = Wr + (size_t)l * 65536; out = WlrT + (size_t)l * 131072 + 65536;
            gamma = ln_g + l * 256; K = 256; N = 256; kb = r >> 2; nb = r & 3; }
        else if (bid < 216) { int i = bid - 200; in = h1_w; out = h1T; K = 256; N = 256; kb = i >> 2; nb = i & 3; }
        else                { int i = bid - 216; in = h2_w; out = h2T; K = 256; N = 128; kb = i >> 1; nb = i & 1; }
        const int k0 = kb * 64, n0 = nb * 64;
        {
            int kl = tid >> 2, np = (tid & 3) * 16;
            const float* ip = in + (size_t)(k0 + kl) * N + n0 + np;
            float4 a = *(const float4*)(ip + 0);
            float4 b = *(const float4*)(ip + 4);
            float4 c = *(const float4*)(ip + 8);
            float4 d = *(const float4*)(ip + 12);
            t[kl][np + 0] = a.x; t[kl][np + 1] = a.y; t[kl][np + 2] = a.z; t[kl][np + 3] = a.w;
            t[kl][np + 4] = b.x; t[kl][np + 5] = b.y; t[kl][np + 6] = b.z; t[kl][np + 7] = b.w;
            t[kl][np + 8] = c.x; t[kl][np + 9] = c.y; t[kl][np +10] = c.z; t[kl][np +11] = c.w;
            t[kl][np +12] = d.x; t[kl][np +13] = d.y; t[kl][np +14] = d.z; t[kl][np +15] = d.w;
        }
        __syncthreads();
        {
            int nl = tid >> 2, kp = (tid & 3) * 16;
            u16x8 o0, o1;
#pragma unroll
            for (int i = 0; i < 8; ++i) {
                float g0 = gamma ? gamma[k0 + kp + i] : 1.f;
                float g1 = gamma ? gamma[k0 + kp + 8 + i] : 1.f;
                o0[i] = __half_as_ushort(__float2half(t[kp + i][nl] * g0));
                o1[i] = __half_as_ushort(__float2half(t[kp + 8 + i][nl] * g1));
            }
            unsigned short* op = (unsigned short*)out + (size_t)(n0 + nl) * K + k0 + kp;
            *(u16x8*)(op + 0) = o0;
            *(u16x8*)(op + 8) = o1;
        }
    } else if (bid < 236) {
        int i = bid - 224, l = i >> 1, side = i & 1, n = tid;
        const float* W = side ? Wr : Wl;
        const float* b = side ? br : bl;
        const float* lb = ln_b + l * 256;
        const float* Wp = W + (size_t)l * 65536;
        float acc = b[l * 256 + n];
        for (int k = 0; k < 256; ++k) acc = fmaf(lb[k], Wp[(size_t)k * 256 + n], acc);
        biasLR[l * 512 + side * 256 + n] = acc;
    } else if (bid < 242) {
        int l = bid - 236;
        att_h[l * 256 + tid] = __float2half(att[l * 256 + tid]);
    } else if (tid == 0) {
        float m = -1e30f;
        for (int l = 0; l < LL; ++l) m = fmaxf(m, sw[l]);
        float e[LL]; float s = 0.f;
        for (int l = 0; l < LL; ++l) { e[l] = __expf(sw[l] - m); s += e[l]; }
        float w[LL];
        for (int l = 0; l < LL; ++l) { w[l] = e[l] / s; wsm[l] = w[l]; }
        for (int l = 0; l < LL; ++l) {
            float S = 0.f;
            for (int k = l; k < LL; ++k) S += w[k];
            wsm[8 + l] = S;   // suffix sums
        }
    }
}

// ------- generic fp32 -> fp16 -------
__global__ __launch_bounds__(256) void cvt_h_k(const float* __restrict__ in,
                                               __half* __restrict__ out, int n)
{
    int i = blockIdx.x * 256 + threadIdx.x;
    if (i < n) out[i] = __float2half(in[i]);
}

// ------- fp16 MFMA GEMM, 128x128 tile, BK=64, global_load_lds staging, XOR swizzle ----
// OUT: 0 = fp32 Cv, 1 = fp16 Cv, 2 = split (cols<256 -> fp8 C8, cols>=256 -> fp16 C16)
template<int ACT, int OUT>
__global__ __launch_bounds__(256) void gemm_h_k(
    const __half* __restrict__ A, const __half* __restrict__ Bt,
    const float* __restrict__ bias, const float* __restrict__ g2,
    const float* __restrict__ b2, void* __restrict__ Cv,
    unsigned char* __restrict__ C8, __half* __restrict__ C16,
    int M, int K, int N)
{
    __shared__ _Float16 As[128 * 64];
    __shared__ _Float16 Bs[128 * 64];
    const int tid = threadIdx.x, lane = tid & 63, wave = tid >> 6;
    const int bm = blockIdx.x * 128, bn = blockIdx.y * 128;
    const int wm = (wave & 1) * 64, wn = (wave >> 1) * 64;
    const int mrow = lane & 15;
    const int sg = lane >> 3;
    const int sc = (lane & 7) ^ sg;

    f32x4 acc[4][4];
#pragma unroll
    for (int i = 0; i < 4; ++i)
#pragma unroll
        for (int j = 0; j < 4; ++j) acc[i][j] = (f32x4){0.f, 0.f, 0.f, 0.f};

    for (int k0 = 0; k0 < K; k0 += 64) {
#pragma unroll
        for (int t = 0; t < 4; ++t) {
            int R = 32 * wave + 8 * t;
            int ar = bm + R + sg; if (ar >= M) ar = M - 1;
            GLD16(A + (size_t)ar * K + k0 + sc * 8, &As[R * 64]);
        }
#pragma unroll
        for (int t = 0; t < 4; ++t) {
            int R = 32 * wave + 8 * t;
            GLD16(Bt + (size_t)(bn + R + sg) * K + k0 + sc * 8, &Bs[R * 64]);
        }
        __syncthreads();
#pragma unroll
        for (int s2 = 0; s2 < 2; ++s2) {
            const int c = s2 * 4 + (lane >> 4);
            f16x8 af[4], bf[4];
#pragma unroll
            for (int i = 0; i < 4; ++i) {
                int r = wm + 16 * i + mrow;
                af[i] = *(const f16x8*)&As[r * 64 + ((c ^ (r & 7)) * 8)];
            }
#pragma unroll
            for (int j = 0; j < 4; ++j) {
                int r = wn + 16 * j + mrow;
                bf[j] = *(const f16x8*)&Bs[r * 64 + ((c ^ (r & 7)) * 8)];
            }
#pragma unroll
            for (int i = 0; i < 4; ++i)
#pragma unroll
                for (int j = 0; j < 4; ++j)
                    acc[i][j] = __builtin_amdgcn_mfma_f32_16x16x32_f16(af[i], bf[j], acc[i][j], 0, 0, 0);
        }
        __syncthreads();
    }

    const float inv_s = 0.9999950000374997f; // 1/sqrt(1+1e-5)
    const int rq = (lane >> 4) * 4;
    float bsj[4], gj[4], bbj[4];
#pragma unroll
    for (int j = 0; j < 4; ++j) {
        int cc = bn + wn + 16 * j + mrow;
        bsj[j] = bias[cc];
        if constexpr (ACT == 1) { gj[j] = g2[cc]; bbj[j] = b2[cc]; }
    }
#pragma unroll
    for (int i = 0; i < 4; ++i)
#pragma unroll
        for (int r = 0; r < 4; ++r) {
            int grow = bm + wm + 16 * i + rq + r;
            if (grow >= M) continue;
#pragma unroll
            for (int j = 0; j < 4; ++j) {
                int cc = bn + wn + 16 * j + mrow;
                float v = acc[i][j][r] + bsj[j];
                if constexpr (ACT == 1) v = leaky(v * inv_s * gj[j] + bbj[j], 0.1f);
                else if constexpr (ACT == 2) v = leaky(v, 0.1f);
                if constexpr (OUT == 0)      ((float*)Cv)[(size_t)grow * N + cc] = v;
                else if constexpr (OUT == 1) ((__half*)Cv)[(size_t)grow * N + cc] = __float2half(v);
                else {
                    if (bn < 256) C8[(size_t)grow * 256 + cc] = f2fp8(v);
                    else          C16[(size_t)grow * 256 + (cc - 256)] = __float2half(v);
                }
            }
        }
}

// ------- entry LN: norm = (h16 - mu)*rsig -> fp16; hacc init = h16 -------
__global__ __launch_bounds__(256) void ln_norm_k(const __half* __restrict__ h16,
                                                 __half* __restrict__ hacc,
                                                 __half* __restrict__ normed, int N)
{
    int wv = blockIdx.x * 4 + (threadIdx.x >> 6);
    if (wv >= N) return;
    int lane = threadIdx.x & 63;
    size_t off = (size_t)wv * 256 + lane * 4;
    uint2 u = *(const uint2*)((const unsigned short*)h16 + off);
    f16x2 p0 = asf2(u.x), p1 = asf2(u.y);
    float v0 = (float)p0[0], v1 = (float)p0[1], v2 = (float)p1[0], v3 = (float)p1[1];
    float s = v0 + v1 + v2 + v3;
#pragma unroll
    for (int o = 1; o < 64; o <<= 1) s += __shfl_xor(s, o);
    float m = s * (1.f / 256.f);
    float d0 = v0 - m, d1 = v1 - m, d2 = v2 - m, d3 = v3 - m;
    float q = d0 * d0 + d1 * d1 + d2 * d2 + d3 * d3;
#pragma unroll
    for (int o = 1; o < 64; o <<= 1) q += __shfl_xor(q, o);
    float rs = rsqrtf(q * (1.f / 256.f) + EPSF);
    *(uint2*)((unsigned short*)hacc + off) = u;
    uint2 o2;
    o2.x = asu2(pk2(d0 * rs, d1 * rs));
    o2.y = asu2(pk2(d2 * rs, d3 * rs));
    *(uint2*)((unsigned short*)normed + off) = o2;
}

// ---------------- CSR build ----------------
__global__ __launch_bounds__(256) void hist_k(const int* __restrict__ ei, int E, int N,
                                              int* __restrict__ counts)
{
    int e = blockIdx.x * 256 + threadIdx.x;
    int Etot = E + N;
    if (e >= Etot) return;
    int d = (e < E) ? ei[E + e] : (e - E);
    atomicAdd(&counts[d], 1);
}

// single-pass scan: 1024 threads x 49 contiguous items
__global__ __launch_bounds__(1024) void scan_k(const int* __restrict__ counts,
                                               int* __restrict__ offsets, int N, int Etot)
{
    __shared__ int wsum[16];
    const int t = threadIdx.x;
    const int base = t * 49;
    int s = 0;
#pragma unroll 1
    for (int i = 0; i < 49; ++i) { int idx = base + i; if (idx < N) s += counts[idx]; }
    int lane = t & 63, wvi = t >> 6;
    int ps = s;
    for (int off = 1; off < 64; off <<= 1) {
        int u = __shfl_up(ps, off);
        if (lane >= off) ps += u;
    }
    if (lane == 63) wsum[wvi] = ps;
    __syncthreads();
    if (t == 0) {
        int run = 0;
        for (int i = 0; i < 16; ++i) { int v = wsum[i]; wsum[i] = run; run += v; }
    }
    __syncthreads();
    int run = wsum[wvi] + ps - s;   // exclusive prefix for this thread
#pragma unroll 1
    for (int i = 0; i < 49; ++i) {
        int idx = base + i;
        if (idx < N) { offsets[idx] = run; run += counts[idx]; }
    }
    if (t == 1023) offsets[N] = Etot;
}

__global__ __launch_bounds__(256) void scatter_k(const int* __restrict__ ei, int E, int N,
                                                 int* __restrict__ cursor, int* __restrict__ eidx)
{
    int e = blockIdx.x * 256 + threadIdx.x;
    int Etot = E + N;
    if (e >= Etot) return;
    int s, d;
    if (e < E) { s = ei[e]; d = ei[E + e]; }
    else       { s = e - E; d = s; }
    int pos = atomicAdd(&cursor[d], 1);
    eidx[pos] = s;
}

// ------- Edge aggregation: wave/node, 4 slots x 16 lanes x 16 ch; fp8 xl gather -------
__global__ __launch_bounds__(256) void edge_k(
    const unsigned char* __restrict__ xl8, const __half* __restrict__ xr16,
    const __half* __restrict__ atth, const float* __restrict__ convb,
    const int* __restrict__ offsets, const int* __restrict__ eidx,
    __half* __restrict__ h16, __half* __restrict__ hacc,
    __half* __restrict__ normed,
    const float* __restrict__ wsm, const float* __restrict__ scales,
    int layer, int N)
{
    int wv = blockIdx.x * 4 + (threadIdx.x >> 6);
    if (wv >= N) return;
    const int lane = threadIdx.x & 63;
    const int slot = lane >> 4, sl = lane & 15;
    const int c0 = sl * 16;               // this lane's 16-channel segment (head = sl>>1)

    f16x2 atv[8], xrv[8];
    {
        const unsigned short* ap = (const unsigned short*)atth + c0;
        const unsigned short* xp = (const unsigned short*)xr16 + (size_t)wv * 256 + c0;
        uint4 a0 = *(const uint4*)ap, a1 = *(const uint4*)(ap + 8);
        uint4 x0 = *(const uint4*)xp, x1 = *(const uint4*)(xp + 8);
        atv[0]=asf2(a0.x); atv[1]=asf2(a0.y); atv[2]=asf2(a0.z); atv[3]=asf2(a0.w);
        atv[4]=asf2(a1.x); atv[5]=asf2(a1.y); atv[6]=asf2(a1.z); atv[7]=asf2(a1.w);
        xrv[0]=asf2(x0.x); xrv[1]=asf2(x0.y); xrv[2]=asf2(x0.z); xrv[3]=asf2(x0.w);
        xrv[4]=asf2(x1.x); xrv[5]=asf2(x1.y); xrv[6]=asf2(x1.z); xrv[7]=asf2(x1.w);
    }
    const int e0 = offsets[wv], e1 = offsets[wv + 1], e1m = e1 - 1;
    f16x2 a2[8];
#pragma unroll
    for (int p = 0; p < 8; ++p) a2[p] = pk2(0.f, 0.f);
    float den = 0.f;

    for (int base = e0; base < e1; base += 4) {
        int e = base + slot;
        bool v = e < e1;
        int s = eidx[v ? e : e1m];
        uint4 w = *(const uint4*)(xl8 + (size_t)s * 256 + c0);   // 16 fp8 ch
        f16x2 xv[8];
        xv[0] = __builtin_amdgcn_cvt_scalef32_pk_f16_fp8(w.x, 1.0f, false);
        xv[1] = __builtin_amdgcn_cvt_scalef32_pk_f16_fp8(w.x, 1.0f, true);
        xv[2] = __builtin_amdgcn_cvt_scalef32_pk_f16_fp8(w.y, 1.0f, false);
        xv[3] = __builtin_amdgcn_cvt_scalef32_pk_f16_fp8(w.y, 1.0f, true);
        xv[4] = __builtin_amdgcn_cvt_scalef32_pk_f16_fp8(w.z, 1.0f, false);
        xv[5] = __builtin_amdgcn_cvt_scalef32_pk_f16_fp8(w.z, 1.0f, true);
        xv[6] = __builtin_amdgcn_cvt_scalef32_pk_f16_fp8(w.w, 1.0f, false);
        xv[7] = __builtin_amdgcn_cvt_scalef32_pk_f16_fp8(w.w, 1.0f, true);
        float pm = 0.f;
#pragma unroll
        for (int p = 0; p < 8; ++p) {
            f16x2 t = lrelu2_02(xv[p] + xrv[p]);
            pm = __builtin_amdgcn_fdot2(t, atv[p], pm, false);
        }
        pm += __shfl_xor(pm, 1);             // head = 2 lanes (32 ch)
        float exf = v ? __expf(pm) : 0.f;
        den += exf;
        _Float16 eh = (_Float16)exf;
        f16x2 e2; e2[0] = eh; e2[1] = eh;
#pragma unroll
        for (int p = 0; p < 8; ++p) a2[p] += xv[p] * e2;
    }

    // combine across the 4 slots (lane bits 4,5)
    den += __shfl_xor(den, 16); den += __shfl_xor(den, 32);
#pragma unroll
    for (int p = 0; p < 8; ++p) {
        a2[p] += asf2((unsigned int)__shfl_xor((int)asu2(a2[p]), 16));
        a2[p] += asf2((unsigned int)__shfl_xor((int)asu2(a2[p]), 32));
    }

    // all-lane epilogue: lane handles 4 channels cc = c0 + 4*slot (a2[2*slot], a2[2*slot+1])
    const int p0 = 2 * slot;
    const float inv = 1.f / den;
    const float sc = scales[layer], Sl = wsm[8 + layer];
    const int cc = c0 + 4 * slot;
    const size_t rb = (size_t)wv * 256 + cc;
    float4 cb = *(const float4*)(convb + cc);
    uint2 hu = *(const uint2*)((const unsigned short*)h16 + rb);
    f16x2 h0 = asf2(hu.x), h1 = asf2(hu.y);
    float d00 = sc * leaky(fmaf((float)a2[p0][0],     inv, cb.x), 0.1f);
    float d01 = sc * leaky(fmaf((float)a2[p0][1],     inv, cb.y), 0.1f);
    float d10 = sc * leaky(fmaf((float)a2[p0 + 1][0], inv, cb.z), 0.1f);
    float d11 = sc * leaky(fmaf((float)a2[p0 + 1][1], inv, cb.w), 0.1f);
    float hn0 = (float)h0[0] + d00, hn1 = (float)h0[1] + d01;
    float hn2 = (float)h1[0] + d10, hn3 = (float)h1[1] + d11;

    // hacc += S_l * d   (hsum = h_entry + sum_l S_l d_l; softmax weights sum to 1)
    {
        uint2 au = *(const uint2*)((const unsigned short*)hacc + rb);
        f16x2 A0 = asf2(au.x), A1 = asf2(au.y);
        uint2 ao;
        ao.x = asu2(pk2(fmaf(Sl, d00, (float)A0[0]), fmaf(Sl, d01, (float)A0[1])));
        ao.y = asu2(pk2(fmaf(Sl, d10, (float)A1[0]), fmaf(Sl, d11, (float)A1[1])));
        *(uint2*)((unsigned short*)hacc + rb) = ao;
    }

    if (layer != LL - 1) {
        uint2 ho;
        ho.x = asu2(pk2(hn0, hn1));
        ho.y = asu2(pk2(hn2, hn3));
        *(uint2*)((unsigned short*)h16 + rb) = ho;
        // LN stats across the full wave (each lane holds 4 distinct channels)
        float s1 = hn0 + hn1 + hn2 + hn3;
#pragma unroll
        for (int o = 1; o < 64; o <<= 1) s1 += __shfl_xor(s1, o);
        float m = s1 * (1.f / 256.f);
        float dd0 = hn0 - m, dd1 = hn1 - m, dd2 = hn2 - m, dd3 = hn3 - m;
        float qv = dd0 * dd0 + dd1 * dd1 + dd2 * dd2 + dd3 * dd3;
#pragma unroll
        for (int o = 1; o < 64; o <<= 1) qv += __shfl_xor(qv, o);
        float rs = rsqrtf(qv * (1.f / 256.f) + EPSF);
        uint2 no;
        no.x = asu2(pk2(dd0 * rs, dd1 * rs));
        no.y = asu2(pk2(dd2 * rs, dd3 * rs));
        *(uint2*)((unsigned short*)normed + rb) = no;
    }
}

// ---------------- final y2[N,128] @ h3_w[128,1] + h3_b ----------------
__global__ __launch_bounds__(256) void out_k(const float* __restrict__ y2,
                                             const float* __restrict__ w,
                                             const float* __restrict__ b,
                                             float* __restrict__ out, int N)
{
    int wv = blockIdx.x * 4 + (threadIdx.x >> 6);
    if (wv >= N) return;
    int lane = threadIdx.x & 63;
    float2 v = *(const float2*)(y2 + (size_t)wv * 128 + lane * 2);
    float2 ww = *(const float2*)(w + lane * 2);
    float pm = v.x * ww.x + v.y * ww.y;
#pragma unroll
    for (int off = 1; off < 64; off <<= 1) pm += __shfl_xor(pm, off);
    if (lane == 0) out[wv] = pm + b[0];
}

extern "C" void kernel_launch(void* const* d_in, const int* in_sizes, int n_in,
                              void* d_out, int out_size, void* d_ws, size_t ws_size,
                              hipStream_t stream)
{
    const int N = NN, E = EE, Etot = EE + NN;
    const float* x      = (const float*)d_in[0];
    const int*   ei     = (const int*)  d_in[1];
    const float* win_w  = (const float*)d_in[2];
    const float* win_b  = (const float*)d_in[3];
    const float* bn1_g  = (const float*)d_in[4];
    const float* bn1_b  = (const float*)d_in[5];
    const float* ln_g   = (const float*)d_in[6];
    const float* ln_b   = (const float*)d_in[7];
    const float* Wl     = (const float*)d_in[8];
    const float* bl     = (const float*)d_in[9];
    const float* Wr     = (const float*)d_in[10];
    const float* br     = (const float*)d_in[11];
    const float* att    = (const float*)d_in[12];
    const float* conv_b = (const float*)d_in[13];
    const float* scales = (const float*)d_in[14];
    const float* sw     = (const float*)d_in[15];
    const float* h1_w   = (const float*)d_in[16];
    const float* h1_b   = (const float*)d_in[17];
    const float* bn2_g  = (const float*)d_in[18];
    const float* bn2_b  = (const float*)d_in[19];
    const float* h2_w   = (const float*)d_in[20];
    const float* h2_b   = (const float*)d_in[21];
    const float* h3_w   = (const float*)d_in[22];
    const float* h3_b   = (const float*)d_in[23];

    char* p = (char*)d_ws;
    auto take = [&](size_t b) -> char* {
        char* q = p; p += (b + 255) & ~(size_t)255; return q;
    };
    __half* h16     = (__half*)take((size_t)N * 256 * 2);
    __half* hacc    = (__half*)take((size_t)N * 256 * 2);
    __half* norm    = (__half*)take((size_t)N * 256 * 2);
    unsigned char* xl8 = (unsigned char*)take((size_t)N * 256);
    __half* xr16    = (__half*)take((size_t)N * 256 * 2);
    __half* xh      = (__half*)take((size_t)N * 128 * 2);
    float*  y2      = (float*)take((size_t)N * 128 * 4);
    float* wsm      = (float*)take(256);
    int*   offsets  = (int*)take((size_t)(N + 1) * 4);
    int*   cursor   = (int*)take((size_t)N * 4);
    int*   eidx     = (int*)take((size_t)Etot * 4);
    __half* winT    = (__half*)take((size_t)256 * 128 * 2);
    __half* WlrT    = (__half*)take((size_t)LL * 512 * 256 * 2);
    __half* h1T     = (__half*)take((size_t)256 * 256 * 2);
    __half* h2T     = (__half*)take((size_t)128 * 256 * 2);
    __half* att_h   = (__half*)take((size_t)LL * 256 * 2);
    float* biasLR   = (float*)take((size_t)LL * 512 * 4);
    __half* y1b = xr16;   // xr16 dead after layer-5 edge_k

    const int EB = (Etot + 255) / 256;
    const int NB = (N + 3) / 4;

    // CSR build
    hipMemsetAsync(cursor, 0, (size_t)N * 4, stream);
    hist_k<<<EB, 256, 0, stream>>>(ei, E, N, cursor);
    scan_k<<<1, 1024, 0, stream>>>(cursor, offsets, N, Etot);
    hipMemcpyAsync(cursor, offsets, (size_t)N * 4, hipMemcpyDeviceToDevice, stream);
    scatter_k<<<EB, 256, 0, stream>>>(ei, E, N, cursor, eidx);

    // fused prep: transposes(+gamma fold), biasfold(+beta fold), att cvt, softmax+suffix
    prep_k<<<243, 256, 0, stream>>>(win_w, Wl, Wr, h1_w, h2_w, ln_g, ln_b, bl, br, att, sw,
                                    winT, WlrT, h1T, h2T, att_h, biasLR, wsm);
    cvt_h_k<<<(N * 128 + 255) / 256, 256, 0, stream>>>(x, xh, N * 128);

    dim3 g2d((N + 127) / 128, 2);   // 391 x 2
    dim3 g4d((N + 127) / 128, 4);   // 391 x 4

    // entry: h16 = leaky(bn1(x @ win_w + win_b), 0.1) fp16; norm + hacc init
    gemm_h_k<1, 1><<<g2d, 256, 0, stream>>>(xh, winT, win_b, bn1_g, bn1_b, h16,
                                            nullptr, nullptr, N, 128, 256);
    ln_norm_k<<<NB, 256, 0, stream>>>(h16, hacc, norm, N);

    for (int l = 0; l < LL; ++l) {
        gemm_h_k<0, 2><<<g4d, 256, 0, stream>>>(norm, WlrT + (size_t)l * 131072,
                                                biasLR + l * 512, nullptr, nullptr,
                                                nullptr, xl8, xr16, N, 256, 512);
        edge_k<<<NB, 256, 0, stream>>>(xl8, xr16, att_h + l * 256, conv_b + l * 256,
                                       offsets, eidx, h16, hacc, norm,
                                       wsm, scales, l, N);
    }

    // exit MLP on hacc (= softmax-weighted layer sum, fp16)
    gemm_h_k<1, 1><<<g2d, 256, 0, stream>>>(hacc, h1T, h1_b, bn2_g, bn2_b, y1b,
                                            nullptr, nullptr, N, 256, 256);
    gemm_h_k<2, 0><<<dim3((N + 127) / 128, 1), 256, 0, stream>>>(
        y1b, h2T, h2_b, nullptr, nullptr, y2, nullptr, nullptr, N, 256, 128);
    out_k<<<NB, 256, 0, stream>>>(y2, h3_w, h3_b, (float*)d_out, N);
}

// Round 8
// 879.448 us; speedup vs baseline: 2.9203x; 1.1254x over previous
//
#include <hip/hip_runtime.h>
#include <hip/hip_fp16.h>

#define NN 50000
#define EE 800000
#define LL 6
constexpr float EPSF = 1e-5f;

typedef _Float16 f16x8 __attribute__((ext_vector_type(8)));
typedef _Float16 f16x2 __attribute__((ext_vector_type(2)));
typedef float f32x4 __attribute__((ext_vector_type(4)));
typedef unsigned short u16x8 __attribute__((ext_vector_type(8)));

__device__ __forceinline__ float leaky(float v, float s) { return v > 0.f ? v : s * v; }

__device__ __forceinline__ f16x2 asf2(unsigned int u) {
    union { unsigned int u; f16x2 f; } x; x.u = u; return x.f;
}
__device__ __forceinline__ unsigned int asu2(f16x2 f) {
    union { f16x2 f; unsigned int u; } x; x.f = f; return x.u;
}
__device__ __forceinline__ f16x2 lrelu2_02(f16x2 v) {
    return __builtin_elementwise_max(v, v * (_Float16)0.2f);
}
__device__ __forceinline__ f16x2 pk2(float a, float b) {
    f16x2 r; r[0] = (_Float16)a; r[1] = (_Float16)b; return r;
}
// fp32 -> one fp8 e4m3 byte
__device__ __forceinline__ unsigned char f2fp8(float v) {
    return (unsigned char)(__builtin_amdgcn_cvt_pk_fp8_f32(v, v, 0, false) & 0xff);
}

// async global->LDS, 16B per lane
#define GLD16(gp, sp) __builtin_amdgcn_global_load_lds( \
    (const __attribute__((address_space(1))) unsigned int*)(uintptr_t)(gp), \
    (__attribute__((address_space(3))) unsigned int*)(uintptr_t)(sp), 16, 0, 0)

// ------------- fused prep: all transposes + biasfold + att cvt + softmax -------------
__global__ __launch_bounds__(256) void prep_k(
    const float* __restrict__ win_w, const float* __restrict__ Wl,
    const float* __restrict__ Wr, const float* __restrict__ h1_w,
    const float* __restrict__ h2_w, const float* __restrict__ ln_g,
    const float* __restrict__ ln_b, const float* __restrict__ bl,
    const float* __restrict__ br, const float* __restrict__ att,
    const float* __restrict__ sw,
    __half* __restrict__ winT, __half* __restrict__ WlrT,
    __half* __restrict__ h1T, __half* __restrict__ h2T,
    __half* __restrict__ att_h, float* __restrict__ biasLR, float* __restrict__ wsm)
{
    __shared__ float t[64][65];
    const int bid = blockIdx.x, tid = threadIdx.x;
    if (bid < 224) {
        const float* in; __half* out; const float* gamma = nullptr;
        int K, N, kb, nb;
        if (bid < 8)        { in = win_w; out = winT; K = 128; N = 256; kb = bid >> 2; nb = bid & 3; }
        else if (bid < 104) { int i = bid - 8; int l = i >> 4, r = i & 15;
            in = Wl + (size_t)l * 65536; out = WlrT + (size_t)l * 131072;
            gamma = ln_g + l * 256; K = 256; N = 256; kb = r >> 2; nb = r & 3; }
        else if (bid < 200) { int i = bid - 104; int l = i >> 4, r = i & 15;
            in = Wr + (size_t)l * 65536; out = WlrT + (size_t)l * 131072 + 65536;
            gamma = ln_g + l * 256; K = 256; N = 256; kb = r >> 2; nb = r & 3; }
        else if (bid < 216) { int i = bid - 200; in = h1_w; out = h1T; K = 256; N = 256; kb = i >> 2; nb = i & 3; }
        else                { int i = bid - 216; in = h2_w; out = h2T; K = 256; N = 128; kb = i >> 1; nb = i & 1; }
        const int k0 = kb * 64, n0 = nb * 64;
        {
            int kl = tid >> 2, np = (tid & 3) * 16;
            const float* ip = in + (size_t)(k0 + kl) * N + n0 + np;
            float4 a = *(const float4*)(ip + 0);
            float4 b = *(const float4*)(ip + 4);
            float4 c = *(const float4*)(ip + 8);
            float4 d = *(const float4*)(ip + 12);
            t[kl][np + 0] = a.x; t[kl][np + 1] = a.y; t[kl][np + 2] = a.z; t[kl][np + 3] = a.w;
            t[kl][np + 4] = b.x; t[kl][np + 5] = b.y; t[kl][np + 6] = b.z; t[kl][np + 7] = b.w;
            t[kl][np + 8] = c.x; t[kl][np + 9] = c.y; t[kl][np +10] = c.z; t[kl][np +11] = c.w;
            t[kl][np +12] = d.x; t[kl][np +13] = d.y; t[kl][np +14] = d.z; t[kl][np +15] = d.w;
        }
        __syncthreads();
        {
            int nl = tid >> 2, kp = (tid & 3) * 16;
            u16x8 o0, o1;
#pragma unroll
            for (int i = 0; i < 8; ++i) {
                float g0 = gamma ? gamma[k0 + kp + i] : 1.f;
                float g1 = gamma ? gamma[k0 + kp + 8 + i] : 1.f;
                o0[i] = __half_as_ushort(__float2half(t[kp + i][nl] * g0));
                o1[i] = __half_as_ushort(__float2half(t[kp + 8 + i][nl] * g1));
            }
            unsigned short* op = (unsigned short*)out + (size_t)(n0 + nl) * K + k0 + kp;
            *(u16x8*)(op + 0) = o0;
            *(u16x8*)(op + 8) = o1;
        }
    } else if (bid < 236) {
        int i = bid - 224, l = i >> 1, side = i & 1, n = tid;
        const float* W = side ? Wr : Wl;
        const float* b = side ? br : bl;
        const float* lb = ln_b + l * 256;
        const float* Wp = W + (size_t)l * 65536;
        float acc = b[l * 256 + n];
        for (int k = 0; k < 256; ++k) acc = fmaf(lb[k], Wp[(size_t)k * 256 + n], acc);
        biasLR[l * 512 + side * 256 + n] = acc;
    } else if (bid < 242) {
        int l = bid - 236;
        att_h[l * 256 + tid] = __float2half(att[l * 256 + tid]);
    } else if (tid == 0) {
        float m = -1e30f;
        for (int l = 0; l < LL; ++l) m = fmaxf(m, sw[l]);
        float e[LL]; float s = 0.f;
        for (int l = 0; l < LL; ++l) { e[l] = __expf(sw[l] - m); s += e[l]; }
        float w[LL];
        for (int l = 0; l < LL; ++l) { w[l] = e[l] / s; wsm[l] = w[l]; }
        for (int l = 0; l < LL; ++l) {
            float S = 0.f;
            for (int k = l; k < LL; ++k) S += w[k];
            wsm[8 + l] = S;   // suffix sums
        }
    }
}

// ------- generic fp32 -> fp16 -------
__global__ __launch_bounds__(256) void cvt_h_k(const float* __restrict__ in,
                                               __half* __restrict__ out, int n)
{
    int i = blockIdx.x * 256 + threadIdx.x;
    if (i < n) out[i] = __float2half(in[i]);
}

// ------- fp16 MFMA GEMM, 128x128 tile, BK=64, global_load_lds staging, XOR swizzle ----
// OUT: 0 = fp32 Cv, 1 = fp16 Cv, 2 = split (cols<256 -> fp8 C8, cols>=256 -> fp16 C16)
template<int ACT, int OUT>
__global__ __launch_bounds__(256) void gemm_h_k(
    const __half* __restrict__ A, const __half* __restrict__ Bt,
    const float* __restrict__ bias, const float* __restrict__ g2,
    const float* __restrict__ b2, void* __restrict__ Cv,
    unsigned char* __restrict__ C8, __half* __restrict__ C16,
    int M, int K, int N)
{
    __shared__ _Float16 As[128 * 64];
    __shared__ _Float16 Bs[128 * 64];
    const int tid = threadIdx.x, lane = tid & 63, wave = tid >> 6;
    const int bm = blockIdx.x * 128, bn = blockIdx.y * 128;
    const int wm = (wave & 1) * 64, wn = (wave >> 1) * 64;
    const int mrow = lane & 15;
    const int sg = lane >> 3;
    const int sc = (lane & 7) ^ sg;

    f32x4 acc[4][4];
#pragma unroll
    for (int i = 0; i < 4; ++i)
#pragma unroll
        for (int j = 0; j < 4; ++j) acc[i][j] = (f32x4){0.f, 0.f, 0.f, 0.f};

    for (int k0 = 0; k0 < K; k0 += 64) {
#pragma unroll
        for (int t = 0; t < 4; ++t) {
            int R = 32 * wave + 8 * t;
            int ar = bm + R + sg; if (ar >= M) ar = M - 1;
            GLD16(A + (size_t)ar * K + k0 + sc * 8, &As[R * 64]);
        }
#pragma unroll
        for (int t = 0; t < 4; ++t) {
            int R = 32 * wave + 8 * t;
            GLD16(Bt + (size_t)(bn + R + sg) * K + k0 + sc * 8, &Bs[R * 64]);
        }
        __syncthreads();
#pragma unroll
        for (int s2 = 0; s2 < 2; ++s2) {
            const int c = s2 * 4 + (lane >> 4);
            f16x8 af[4], bf[4];
#pragma unroll
            for (int i = 0; i < 4; ++i) {
                int r = wm + 16 * i + mrow;
                af[i] = *(const f16x8*)&As[r * 64 + ((c ^ (r & 7)) * 8)];
            }
#pragma unroll
            for (int j = 0; j < 4; ++j) {
                int r = wn + 16 * j + mrow;
                bf[j] = *(const f16x8*)&Bs[r * 64 + ((c ^ (r & 7)) * 8)];
            }
#pragma unroll
            for (int i = 0; i < 4; ++i)
#pragma unroll
                for (int j = 0; j < 4; ++j)
                    acc[i][j] = __builtin_amdgcn_mfma_f32_16x16x32_f16(af[i], bf[j], acc[i][j], 0, 0, 0);
        }
        __syncthreads();
    }

    const float inv_s = 0.9999950000374997f; // 1/sqrt(1+1e-5)
    const int rq = (lane >> 4) * 4;
    float bsj[4], gj[4], bbj[4];
#pragma unroll
    for (int j = 0; j < 4; ++j) {
        int cc = bn + wn + 16 * j + mrow;
        bsj[j] = bias[cc];
        if constexpr (ACT == 1) { gj[j] = g2[cc]; bbj[j] = b2[cc]; }
    }
#pragma unroll
    for (int i = 0; i < 4; ++i)
#pragma unroll
        for (int r = 0; r < 4; ++r) {
            int grow = bm + wm + 16 * i + rq + r;
            if (grow >= M) continue;
#pragma unroll
            for (int j = 0; j < 4; ++j) {
                int cc = bn + wn + 16 * j + mrow;
                float v = acc[i][j][r] + bsj[j];
                if constexpr (ACT == 1) v = leaky(v * inv_s * gj[j] + bbj[j], 0.1f);
                else if constexpr (ACT == 2) v = leaky(v, 0.1f);
                if constexpr (OUT == 0)      ((float*)Cv)[(size_t)grow * N + cc] = v;
                else if constexpr (OUT == 1) ((__half*)Cv)[(size_t)grow * N + cc] = __float2half(v);
                else {
                    if (bn < 256) C8[(size_t)grow * 256 + cc] = f2fp8(v);
                    else          C16[(size_t)grow * 256 + (cc - 256)] = __float2half(v);
                }
            }
        }
}

// ------- entry LN: norm = (h16 - mu)*rsig -> fp16; hacc init = h16 -------
__global__ __launch_bounds__(256) void ln_norm_k(const __half* __restrict__ h16,
                                                 __half* __restrict__ hacc,
                                                 __half* __restrict__ normed, int N)
{
    int wv = blockIdx.x * 4 + (threadIdx.x >> 6);
    if (wv >= N) return;
    int lane = threadIdx.x & 63;
    size_t off = (size_t)wv * 256 + lane * 4;
    uint2 u = *(const uint2*)((const unsigned short*)h16 + off);
    f16x2 p0 = asf2(u.x), p1 = asf2(u.y);
    float v0 = (float)p0[0], v1 = (float)p0[1], v2 = (float)p1[0], v3 = (float)p1[1];
    float s = v0 + v1 + v2 + v3;
#pragma unroll
    for (int o = 1; o < 64; o <<= 1) s += __shfl_xor(s, o);
    float m = s * (1.f / 256.f);
    float d0 = v0 - m, d1 = v1 - m, d2 = v2 - m, d3 = v3 - m;
    float q = d0 * d0 + d1 * d1 + d2 * d2 + d3 * d3;
#pragma unroll
    for (int o = 1; o < 64; o <<= 1) q += __shfl_xor(q, o);
    float rs = rsqrtf(q * (1.f / 256.f) + EPSF);
    *(uint2*)((unsigned short*)hacc + off) = u;
    uint2 o2;
    o2.x = asu2(pk2(d0 * rs, d1 * rs));
    o2.y = asu2(pk2(d2 * rs, d3 * rs));
    *(uint2*)((unsigned short*)normed + off) = o2;
}

// ---------------- CSR build ----------------
__global__ __launch_bounds__(256) void hist_k(const int* __restrict__ ei, int E, int N,
                                              int* __restrict__ counts)
{
    int e = blockIdx.x * 256 + threadIdx.x;
    int Etot = E + N;
    if (e >= Etot) return;
    int d = (e < E) ? ei[E + e] : (e - E);
    atomicAdd(&counts[d], 1);
}

// ---- 3-phase grid scan: A) block reduce  B) scan block sums  C) local scan + offset ----
__global__ __launch_bounds__(256) void scanA_k(const int* __restrict__ counts,
                                               int* __restrict__ bsum, int N)
{
    int i = blockIdx.x * 256 + threadIdx.x;
    int v = (i < N) ? counts[i] : 0;
    int s = v;
#pragma unroll
    for (int o = 1; o < 64; o <<= 1) s += __shfl_xor(s, o);
    __shared__ int ws[4];
    if ((threadIdx.x & 63) == 0) ws[threadIdx.x >> 6] = s;
    __syncthreads();
    if (threadIdx.x == 0) bsum[blockIdx.x] = ws[0] + ws[1] + ws[2] + ws[3];
}

__global__ __launch_bounds__(256) void scanB_k(const int* __restrict__ bsum,
                                               int* __restrict__ bpre, int nb)
{
    int t = threadIdx.x;
    int v = (t < nb) ? bsum[t] : 0;
    int lane = t & 63, w = t >> 6;
    int incl = v;
#pragma unroll
    for (int o = 1; o < 64; o <<= 1) { int u = __shfl_up(incl, o); if (lane >= o) incl += u; }
    __shared__ int ws[4];
    if (lane == 63) ws[w] = incl;
    __syncthreads();
    if (t == 0) { int run = 0; for (int k = 0; k < 4; ++k) { int x = ws[k]; ws[k] = run; run += x; } }
    __syncthreads();
    if (t < nb) bpre[t] = ws[w] + incl - v;
}

__global__ __launch_bounds__(256) void scanC_k(int* __restrict__ counts,
                                               const int* __restrict__ bpre,
                                               int* __restrict__ offsets, int N, int Etot)
{
    int i = blockIdx.x * 256 + threadIdx.x;
    int v = (i < N) ? counts[i] : 0;
    int lane = threadIdx.x & 63, w = threadIdx.x >> 6;
    int incl = v;
#pragma unroll
    for (int o = 1; o < 64; o <<= 1) { int u = __shfl_up(incl, o); if (lane >= o) incl += u; }
    __shared__ int ws[4];
    if (lane == 63) ws[w] = incl;
    __syncthreads();
    if (threadIdx.x == 0) { int run = 0; for (int k = 0; k < 4; ++k) { int x = ws[k]; ws[k] = run; run += x; } }
    __syncthreads();
    int ex = bpre[blockIdx.x] + ws[w] + incl - v;
    if (i < N) { offsets[i] = ex; counts[i] = ex; }   // counts becomes the scatter cursor
    if (i == 0) offsets[N] = Etot;
}

__global__ __launch_bounds__(256) void scatter_k(const int* __restrict__ ei, int E, int N,
                                                 int* __restrict__ cursor, int* __restrict__ eidx)
{
    int e = blockIdx.x * 256 + threadIdx.x;
    int Etot = E + N;
    if (e >= Etot) return;
    int s, d;
    if (e < E) { s = ei[e]; d = ei[E + e]; }
    else       { s = e - E; d = s; }
    int pos = atomicAdd(&cursor[d], 1);
    eidx[pos] = s;
}

// ------- Edge aggregation: wave/node, 4 slots x 16 lanes x 16 ch; fp8 xl gather -------
__global__ __launch_bounds__(256) void edge_k(
    const unsigned char* __restrict__ xl8, const __half* __restrict__ xr16,
    const __half* __restrict__ atth, const float* __restrict__ convb,
    const int* __restrict__ offsets, const int* __restrict__ eidx,
    __half* __restrict__ h16, __half* __restrict__ hacc,
    __half* __restrict__ normed,
    const float* __restrict__ wsm, const float* __restrict__ scales,
    int layer, int N)
{
    int wv = blockIdx.x * 4 + (threadIdx.x >> 6);
    if (wv >= N) return;
    const int lane = threadIdx.x & 63;
    const int slot = lane >> 4, sl = lane & 15;
    const int c0 = sl * 16;               // this lane's 16-channel segment (head = sl>>1)

    f16x2 atv[8], xrv[8];
    {
        const unsigned short* ap = (const unsigned short*)atth + c0;
        const unsigned short* xp = (const unsigned short*)xr16 + (size_t)wv * 256 + c0;
        uint4 a0 = *(const uint4*)ap, a1 = *(const uint4*)(ap + 8);
        uint4 x0 = *(const uint4*)xp, x1 = *(const uint4*)(xp + 8);
        atv[0]=asf2(a0.x); atv[1]=asf2(a0.y); atv[2]=asf2(a0.z); atv[3]=asf2(a0.w);
        atv[4]=asf2(a1.x); atv[5]=asf2(a1.y); atv[6]=asf2(a1.z); atv[7]=asf2(a1.w);
        xrv[0]=asf2(x0.x); xrv[1]=asf2(x0.y); xrv[2]=asf2(x0.z); xrv[3]=asf2(x0.w);
        xrv[4]=asf2(x1.x); xrv[5]=asf2(x1.y); xrv[6]=asf2(x1.z); xrv[7]=asf2(x1.w);
    }
    const int e0 = offsets[wv], e1 = offsets[wv + 1], e1m = e1 - 1;
    f16x2 a2[8];
#pragma unroll
    for (int p = 0; p < 8; ++p) a2[p] = pk2(0.f, 0.f);
    float den = 0.f;

    for (int base = e0; base < e1; base += 4) {
        int e = base + slot;
        bool v = e < e1;
        int s = eidx[v ? e : e1m];
        uint4 w = *(const uint4*)(xl8 + (size_t)s * 256 + c0);   // 16 fp8 ch
        f16x2 xv[8];
        xv[0] = __builtin_amdgcn_cvt_scalef32_pk_f16_fp8(w.x, 1.0f, false);
        xv[1] = __builtin_amdgcn_cvt_scalef32_pk_f16_fp8(w.x, 1.0f, true);
        xv[2] = __builtin_amdgcn_cvt_scalef32_pk_f16_fp8(w.y, 1.0f, false);
        xv[3] = __builtin_amdgcn_cvt_scalef32_pk_f16_fp8(w.y, 1.0f, true);
        xv[4] = __builtin_amdgcn_cvt_scalef32_pk_f16_fp8(w.z, 1.0f, false);
        xv[5] = __builtin_amdgcn_cvt_scalef32_pk_f16_fp8(w.z, 1.0f, true);
        xv[6] = __builtin_amdgcn_cvt_scalef32_pk_f16_fp8(w.w, 1.0f, false);
        xv[7] = __builtin_amdgcn_cvt_scalef32_pk_f16_fp8(w.w, 1.0f, true);
        float pm = 0.f;
#pragma unroll
        for (int p = 0; p < 8; ++p) {
            f16x2 t = lrelu2_02(xv[p] + xrv[p]);
            pm = __builtin_amdgcn_fdot2(t, atv[p], pm, false);
        }
        pm += __shfl_xor(pm, 1);             // head = 2 lanes (32 ch)
        float exf = v ? __expf(pm) : 0.f;
        den += exf;
        _Float16 eh = (_Float16)exf;
        f16x2 e2; e2[0] = eh; e2[1] = eh;
#pragma unroll
        for (int p = 0; p < 8; ++p) a2[p] += xv[p] * e2;
    }

    // combine across the 4 slots (lane bits 4,5)
    den += __shfl_xor(den, 16); den += __shfl_xor(den, 32);
#pragma unroll
    for (int p = 0; p < 8; ++p) {
        a2[p] += asf2((unsigned int)__shfl_xor((int)asu2(a2[p]), 16));
        a2[p] += asf2((unsigned int)__shfl_xor((int)asu2(a2[p]), 32));
    }

    // all-lane epilogue: lane handles 4 channels cc = c0 + 4*slot (a2[2*slot], a2[2*slot+1])
    const int p0 = 2 * slot;
    const float inv = 1.f / den;
    const float sc = scales[layer], Sl = wsm[8 + layer];
    const int cc = c0 + 4 * slot;
    const size_t rb = (size_t)wv * 256 + cc;
    float4 cb = *(const float4*)(convb + cc);
    uint2 hu = *(const uint2*)((const unsigned short*)h16 + rb);
    f16x2 h0 = asf2(hu.x), h1 = asf2(hu.y);
    float d00 = sc * leaky(fmaf((float)a2[p0][0],     inv, cb.x), 0.1f);
    float d01 = sc * leaky(fmaf((float)a2[p0][1],     inv, cb.y), 0.1f);
    float d10 = sc * leaky(fmaf((float)a2[p0 + 1][0], inv, cb.z), 0.1f);
    float d11 = sc * leaky(fmaf((float)a2[p0 + 1][1], inv, cb.w), 0.1f);
    float hn0 = (float)h0[0] + d00, hn1 = (float)h0[1] + d01;
    float hn2 = (float)h1[0] + d10, hn3 = (float)h1[1] + d11;

    // hacc += S_l * d   (hsum = h_entry + sum_l S_l d_l; softmax weights sum to 1)
    {
        uint2 au = *(const uint2*)((const unsigned short*)hacc + rb);
        f16x2 A0 = asf2(au.x), A1 = asf2(au.y);
        uint2 ao;
        ao.x = asu2(pk2(fmaf(Sl, d00, (float)A0[0]), fmaf(Sl, d01, (float)A0[1])));
        ao.y = asu2(pk2(fmaf(Sl, d10, (float)A1[0]), fmaf(Sl, d11, (float)A1[1])));
        *(uint2*)((unsigned short*)hacc + rb) = ao;
    }

    if (layer != LL - 1) {
        uint2 ho;
        ho.x = asu2(pk2(hn0, hn1));
        ho.y = asu2(pk2(hn2, hn3));
        *(uint2*)((unsigned short*)h16 + rb) = ho;
        // LN stats across the full wave (each lane holds 4 distinct channels)
        float s1 = hn0 + hn1 + hn2 + hn3;
#pragma unroll
        for (int o = 1; o < 64; o <<= 1) s1 += __shfl_xor(s1, o);
        float m = s1 * (1.f / 256.f);
        float dd0 = hn0 - m, dd1 = hn1 - m, dd2 = hn2 - m, dd3 = hn3 - m;
        float qv = dd0 * dd0 + dd1 * dd1 + dd2 * dd2 + dd3 * dd3;
#pragma unroll
        for (int o = 1; o < 64; o <<= 1) qv += __shfl_xor(qv, o);
        float rs = rsqrtf(qv * (1.f / 256.f) + EPSF);
        uint2 no;
        no.x = asu2(pk2(dd0 * rs, dd1 * rs));
        no.y = asu2(pk2(dd2 * rs, dd3 * rs));
        *(uint2*)((unsigned short*)normed + rb) = no;
    }
}

// ---------------- final y2[N,128] @ h3_w[128,1] + h3_b ----------------
__global__ __launch_bounds__(256) void out_k(const float* __restrict__ y2,
                                             const float* __restrict__ w,
                                             const float* __restrict__ b,
                                             float* __restrict__ out, int N)
{
    int wv = blockIdx.x * 4 + (threadIdx.x >> 6);
    if (wv >= N) return;
    int lane = threadIdx.x & 63;
    float2 v = *(const float2*)(y2 + (size_t)wv * 128 + lane * 2);
    float2 ww = *(const float2*)(w + lane * 2);
    float pm = v.x * ww.x + v.y * ww.y;
#pragma unroll
    for (int off = 1; off < 64; off <<= 1) pm += __shfl_xor(pm, off);
    if (lane == 0) out[wv] = pm + b[0];
}

extern "C" void kernel_launch(void* const* d_in, const int* in_sizes, int n_in,
                              void* d_out, int out_size, void* d_ws, size_t ws_size,
                              hipStream_t stream)
{
    const int N = NN, E = EE, Etot = EE + NN;
    const float* x      = (const float*)d_in[0];
    const int*   ei     = (const int*)  d_in[1];
    const float* win_w  = (const float*)d_in[2];
    const float* win_b  = (const float*)d_in[3];
    const float* bn1_g  = (const float*)d_in[4];
    const float* bn1_b  = (const float*)d_in[5];
    const float* ln_g   = (const float*)d_in[6];
    const float* ln_b   = (const float*)d_in[7];
    const float* Wl     = (const float*)d_in[8];
    const float* bl     = (const float*)d_in[9];
    const float* Wr     = (const float*)d_in[10];
    const float* br     = (const float*)d_in[11];
    const float* att    = (const float*)d_in[12];
    const float* conv_b = (const float*)d_in[13];
    const float* scales = (const float*)d_in[14];
    const float* sw     = (const float*)d_in[15];
    const float* h1_w   = (const float*)d_in[16];
    const float* h1_b   = (const float*)d_in[17];
    const float* bn2_g  = (const float*)d_in[18];
    const float* bn2_b  = (const float*)d_in[19];
    const float* h2_w   = (const float*)d_in[20];
    const float* h2_b   = (const float*)d_in[21];
    const float* h3_w   = (const float*)d_in[22];
    const float* h3_b   = (const float*)d_in[23];

    char* p = (char*)d_ws;
    auto take = [&](size_t b) -> char* {
        char* q = p; p += (b + 255) & ~(size_t)255; return q;
    };
    __half* h16     = (__half*)take((size_t)N * 256 * 2);
    __half* hacc    = (__half*)take((size_t)N * 256 * 2);
    __half* norm    = (__half*)take((size_t)N * 256 * 2);
    unsigned char* xl8 = (unsigned char*)take((size_t)N * 256);
    __half* xr16    = (__half*)take((size_t)N * 256 * 2);
    __half* xh      = (__half*)take((size_t)N * 128 * 2);
    float*  y2      = (float*)take((size_t)N * 128 * 4);
    float* wsm      = (float*)take(256);
    int*   offsets  = (int*)take((size_t)(N + 1) * 4);
    int*   cursor   = (int*)take((size_t)N * 4);
    int*   eidx     = (int*)take((size_t)Etot * 4);
    int*   bsum     = (int*)take(256 * 4);
    int*   bpre     = (int*)take(256 * 4);
    __half* winT    = (__half*)take((size_t)256 * 128 * 2);
    __half* WlrT    = (__half*)take((size_t)LL * 512 * 256 * 2);
    __half* h1T     = (__half*)take((size_t)256 * 256 * 2);
    __half* h2T     = (__half*)take((size_t)128 * 256 * 2);
    __half* att_h   = (__half*)take((size_t)LL * 256 * 2);
    float* biasLR   = (float*)take((size_t)LL * 512 * 4);
    __half* y1b = xr16;   // xr16 dead after layer-5 edge_k

    const int EB = (Etot + 255) / 256;
    const int NB = (N + 3) / 4;
    const int SB = (N + 255) / 256;    // 196 scan blocks

    // CSR build (cursor doubles as counts, then as scatter cursor after scanC)
    hipMemsetAsync(cursor, 0, (size_t)N * 4, stream);
    hist_k<<<EB, 256, 0, stream>>>(ei, E, N, cursor);
    scanA_k<<<SB, 256, 0, stream>>>(cursor, bsum, N);
    scanB_k<<<1, 256, 0, stream>>>(bsum, bpre, SB);
    scanC_k<<<SB, 256, 0, stream>>>(cursor, bpre, offsets, N, Etot);
    scatter_k<<<EB, 256, 0, stream>>>(ei, E, N, cursor, eidx);

    // fused prep: transposes(+gamma fold), biasfold(+beta fold), att cvt, softmax+suffix
    prep_k<<<243, 256, 0, stream>>>(win_w, Wl, Wr, h1_w, h2_w, ln_g, ln_b, bl, br, att, sw,
                                    winT, WlrT, h1T, h2T, att_h, biasLR, wsm);
    cvt_h_k<<<(N * 128 + 255) / 256, 256, 0, stream>>>(x, xh, N * 128);

    dim3 g2d((N + 127) / 128, 2);   // 391 x 2
    dim3 g4d((N + 127) / 128, 4);   // 391 x 4

    // entry: h16 = leaky(bn1(x @ win_w + win_b), 0.1) fp16; norm + hacc init
    gemm_h_k<1, 1><<<g2d, 256, 0, stream>>>(xh, winT, win_b, bn1_g, bn1_b, h16,
                                            nullptr, nullptr, N, 128, 256);
    ln_norm_k<<<NB, 256, 0, stream>>>(h16, hacc, norm, N);

    for (int l = 0; l < LL; ++l) {
        gemm_h_k<0, 2><<<g4d, 256, 0, stream>>>(norm, WlrT + (size_t)l * 131072,
                                                biasLR + l * 512, nullptr, nullptr,
                                                nullptr, xl8, xr16, N, 256, 512);
        edge_k<<<NB, 256, 0, stream>>>(xl8, xr16, att_h + l * 256, conv_b + l * 256,
                                       offsets, eidx, h16, hacc, norm,
                                       wsm, scales, l, N);
    }

    // exit MLP on hacc (= softmax-weighted layer sum, fp16)
    gemm_h_k<1, 1><<<g2d, 256, 0, stream>>>(hacc, h1T, h1_b, bn2_g, bn2_b, y1b,
                                            nullptr, nullptr, N, 256, 256);
    gemm_h_k<2, 0><<<dim3((N + 127) / 128, 1), 256, 0, stream>>>(
        y1b, h2T, h2_b, nullptr, nullptr, y2, nullptr, nullptr, N, 256, 128);
    out_k<<<NB, 256, 0, stream>>>(y2, h3_w, h3_b, (float*)d_out, N);
}